// Round 1
// baseline (1722.124 us; speedup 1.0000x reference)
//
#include <hip/hip_runtime.h>
#include <cmath>

// ---------------------------------------------------------------------------
// CrossModalCoherenceMetric: round 0 — correct fp32 baseline.
// G = step@modal^T serves both cosine matrix and softmax logits.
// attention output region doubles as scratch for both raw-dot matrices.
// ---------------------------------------------------------------------------

#define WAVE 64

__device__ __forceinline__ float wave_reduce_sum(float v) {
#pragma unroll
    for (int o = 32; o > 0; o >>= 1) v += __shfl_down(v, o, WAVE);
    return v;
}
__device__ __forceinline__ float wave_reduce_max(float v) {
#pragma unroll
    for (int o = 32; o > 0; o >>= 1) v = fmaxf(v, __shfl_down(v, o, WAVE));
    return v;
}
__device__ __forceinline__ float wave_reduce_min(float v) {
#pragma unroll
    for (int o = 32; o > 0; o >>= 1) v = fminf(v, __shfl_down(v, o, WAVE));
    return v;
}

// ---------------- row L2 norms: one block per row, D=1024, 256 threads -----
__global__ __launch_bounds__(256)
void row_norms_kernel(const float* __restrict__ x, float* __restrict__ nrm) {
    const int row = blockIdx.x;
    const float4 v = ((const float4*)(x + (size_t)row * 1024))[threadIdx.x];
    float s = v.x * v.x + v.y * v.y + v.z * v.z + v.w * v.w;
    s = wave_reduce_sum(s);
    __shared__ float red[4];
    const int lane = threadIdx.x & 63, w = threadIdx.x >> 6;
    if (lane == 0) red[w] = s;
    __syncthreads();
    if (threadIdx.x == 0) {
        float t = red[0] + red[1] + red[2] + red[3];
        nrm[row] = fmaxf(sqrtf(t), 1e-8f);
    }
}

// ---------------- fp32 NT GEMM: C[M x N] = A[M x K] * B[N x K]^T -----------
#define BM 128
#define BN 128
#define BK 16

__global__ __launch_bounds__(256)
void gemm_nt_kernel(const float* __restrict__ A, const float* __restrict__ B,
                    float* __restrict__ C, int M, int N, int K) {
    __shared__ float As[BK][BM];
    __shared__ float Bs[BK][BN];

    const int t    = threadIdx.x;
    const int bm   = blockIdx.y * BM;
    const int bn   = blockIdx.x * BN;
    const int lrow = t >> 1;         // 0..127
    const int lk   = (t & 1) * 8;    // 0 or 8
    const int tm   = (t >> 4) * 8;   // 0..120
    const int tn   = (t & 15) * 8;   // 0..120

    const float* Aptr = A + (size_t)(bm + lrow) * K + lk;
    const float* Bptr = B + (size_t)(bn + lrow) * K + lk;

    float acc[8][8];
#pragma unroll
    for (int i = 0; i < 8; i++)
#pragma unroll
        for (int j = 0; j < 8; j++) acc[i][j] = 0.0f;

    for (int k0 = 0; k0 < K; k0 += BK) {
        const float4 a0 = *(const float4*)(Aptr + k0);
        const float4 a1 = *(const float4*)(Aptr + k0 + 4);
        const float4 b0 = *(const float4*)(Bptr + k0);
        const float4 b1 = *(const float4*)(Bptr + k0 + 4);

        __syncthreads();   // previous iteration finished reading LDS
        As[lk + 0][lrow] = a0.x; As[lk + 1][lrow] = a0.y;
        As[lk + 2][lrow] = a0.z; As[lk + 3][lrow] = a0.w;
        As[lk + 4][lrow] = a1.x; As[lk + 5][lrow] = a1.y;
        As[lk + 6][lrow] = a1.z; As[lk + 7][lrow] = a1.w;
        Bs[lk + 0][lrow] = b0.x; Bs[lk + 1][lrow] = b0.y;
        Bs[lk + 2][lrow] = b0.z; Bs[lk + 3][lrow] = b0.w;
        Bs[lk + 4][lrow] = b1.x; Bs[lk + 5][lrow] = b1.y;
        Bs[lk + 6][lrow] = b1.z; Bs[lk + 7][lrow] = b1.w;
        __syncthreads();

#pragma unroll
        for (int k = 0; k < BK; k++) {
            const float4 x0 = *(const float4*)&As[k][tm];
            const float4 x1 = *(const float4*)&As[k][tm + 4];
            const float4 y0 = *(const float4*)&Bs[k][tn];
            const float4 y1 = *(const float4*)&Bs[k][tn + 4];
            float av[8] = {x0.x, x0.y, x0.z, x0.w, x1.x, x1.y, x1.z, x1.w};
            float bv[8] = {y0.x, y0.y, y0.z, y0.w, y1.x, y1.y, y1.z, y1.w};
#pragma unroll
            for (int i = 0; i < 8; i++)
#pragma unroll
                for (int j = 0; j < 8; j++)
                    acc[i][j] = fmaf(av[i], bv[j], acc[i][j]);
        }
    }

#pragma unroll
    for (int i = 0; i < 8; i++) {
        float* crow = C + (size_t)(bm + tm + i) * N + (bn + tn);
        float4 c0 = {acc[i][0], acc[i][1], acc[i][2], acc[i][3]};
        float4 c1 = {acc[i][4], acc[i][5], acc[i][6], acc[i][7]};
        *(float4*)(crow)     = c0;
        *(float4*)(crow + 4) = c1;
    }
}

// ---------------- negatives: per-row max cosine from raw dots --------------
__global__ __launch_bounds__(256)
void neg_rowmax_kernel(const float* __restrict__ G, const float* __restrict__ na,
                       const float* __restrict__ nn, float* __restrict__ negmax,
                       int M) {
    const int row = blockIdx.x;
    const float* g = G + (size_t)row * M;
    __shared__ float ns[4096];
    for (int i = threadIdx.x; i < M; i += 256) ns[i] = nn[i];
    __syncthreads();
    float cmax = -3.4e38f;
    for (int j = threadIdx.x; j < M; j += 256)
        cmax = fmaxf(cmax, g[j] / ns[j]);
    cmax = wave_reduce_max(cmax);
    __shared__ float red[4];
    const int lane = threadIdx.x & 63, w = threadIdx.x >> 6;
    if (lane == 0) red[w] = cmax;
    __syncthreads();
    if (threadIdx.x == 0) {
        float m = fmaxf(fmaxf(red[0], red[1]), fmaxf(red[2], red[3]));
        negmax[row] = m / na[row];
    }
}

// ---------------- fused softmax row pass (in-place on G) -------------------
// Writes attention in place; emits per_step[row] and weighted-sum w[row].
__global__ __launch_bounds__(256)
void softmax_row_kernel(float* __restrict__ G, const float* __restrict__ na,
                        const float* __restrict__ nb, float* __restrict__ perstep,
                        float* __restrict__ wout, int M) {
    const int row = blockIdx.x;
    float* g = G + (size_t)row * M;
    __shared__ float ns[4096];
    for (int i = threadIdx.x; i < M; i += 256) ns[i] = nb[i];
    __syncthreads();

    const float invT = 1.0f / 0.07f;
    float vals[16];
    float gmax = -3.4e38f, cmax = -3.4e38f;
#pragma unroll
    for (int j = 0; j < 16; j++) {
        const int c = threadIdx.x + j * 256;
        const float v = g[c];
        vals[j] = v;
        gmax = fmaxf(gmax, v);
        cmax = fmaxf(cmax, v / ns[c]);
    }

    __shared__ float red[8];
    __shared__ float bcast[2];
    const int lane = threadIdx.x & 63, w = threadIdx.x >> 6;

    float wg = wave_reduce_max(gmax);
    float wc = wave_reduce_max(cmax);
    if (lane == 0) { red[w] = wg; red[4 + w] = wc; }
    __syncthreads();
    if (threadIdx.x == 0) {
        bcast[0] = fmaxf(fmaxf(red[0], red[1]), fmaxf(red[2], red[3]));
        bcast[1] = fmaxf(fmaxf(red[4], red[5]), fmaxf(red[6], red[7]));
    }
    __syncthreads();
    const float mlog = bcast[0] * invT;
    const float cmaxAll = bcast[1];

    float evals[16];
    float lsum = 0.0f;
#pragma unroll
    for (int j = 0; j < 16; j++) {
        const float e = __expf(vals[j] * invT - mlog);
        evals[j] = e;
        lsum += e;
    }
    lsum = wave_reduce_sum(lsum);
    __syncthreads();           // red[] reuse
    if (lane == 0) red[w] = lsum;
    __syncthreads();
    if (threadIdx.x == 0) bcast[0] = red[0] + red[1] + red[2] + red[3];
    __syncthreads();
    const float invZ = 1.0f / bcast[0];

    float wacc = 0.0f;
#pragma unroll
    for (int j = 0; j < 16; j++) {
        const int c = threadIdx.x + j * 256;
        const float a = evals[j] * invZ;
        g[c] = a;
        wacc += a * vals[j] / ns[c];
    }
    wacc = wave_reduce_sum(wacc);
    __syncthreads();
    if (lane == 0) red[w] = wacc;
    __syncthreads();
    if (threadIdx.x == 0) {
        const float inv_na = 1.0f / na[row];
        perstep[row] = cmaxAll * inv_na;
        wout[row] = (red[0] + red[1] + red[2] + red[3]) * inv_na;
    }
}

// ---------------- finalize scalars -----------------------------------------
__global__ __launch_bounds__(256)
void finalize_kernel(const float* __restrict__ perstep, const float* __restrict__ w,
                     const float* __restrict__ negmax, float* __restrict__ out,
                     int N, size_t NM) {
    float s_a = 0.0f, s_w = 0.0f, s_n = 0.0f, mn = 3.4e38f;
    for (int i = threadIdx.x; i < N; i += 256) {
        const float p = perstep[i];
        s_a += p;
        s_w += w[i];
        s_n += negmax[i];
        mn = fminf(mn, p);
    }
    s_a = wave_reduce_sum(s_a);
    s_w = wave_reduce_sum(s_w);
    s_n = wave_reduce_sum(s_n);
    mn  = wave_reduce_min(mn);
    __shared__ float red[16];
    const int lane = threadIdx.x & 63, wv = threadIdx.x >> 6;
    if (lane == 0) { red[wv] = s_a; red[4 + wv] = s_w; red[8 + wv] = s_n; red[12 + wv] = mn; }
    __syncthreads();
    if (threadIdx.x == 0) {
        const float inv = 1.0f / (float)N;
        const float alignment = (red[0] + red[1] + red[2] + red[3]) * inv;
        const float weighted  = (red[4] + red[5] + red[6] + red[7]) * inv;
        const float neg       = (red[8] + red[9] + red[10] + red[11]) * inv;
        const float minstep   = fminf(fminf(red[12], red[13]), fminf(red[14], red[15]));
        const float contrast  = alignment - neg;
        const float margin    = fmaxf(contrast - 0.2f, 0.0f);
        const float overall   = 0.7f * weighted + 0.3f * contrast;
        out[0] = alignment;
        out[1] = weighted;
        float* p = out + 2 + NM;
        p[0] = contrast;
        p[1] = margin;
        p[2] = alignment;   // positive_alignment
        p[3] = neg;
        // per_step already written at p+4 .. p+4+N
        p[4 + N] = minstep;
        p[5 + N] = overall;
    }
}

// ---------------------------------------------------------------------------
extern "C" void kernel_launch(void* const* d_in, const int* in_sizes, int n_in,
                              void* d_out, int out_size, void* d_ws, size_t ws_size,
                              hipStream_t stream) {
    const float* step  = (const float*)d_in[0];
    const float* modal = (const float*)d_in[1];
    const float* negs  = (const float*)d_in[2];
    float* out = (float*)d_out;

    const int K = 1024;
    const int N = in_sizes[0] / K;   // 8192 steps
    const int M = in_sizes[1] / K;   // 4096 modal
    const size_t NM = (size_t)N * (size_t)M;

    // workspace layout (floats)
    float* ws      = (float*)d_ws;
    float* na      = ws;                 // N
    float* nb      = na + N;             // M
    float* nn      = nb + M;             // M
    float* negmax  = nn + M;             // N
    float* wsum    = negmax + N;         // N

    float* attn    = out + 2;            // attention region, also GEMM scratch
    float* perstep = out + 2 + NM + 4;   // per_step output slot

    // 1. norms
    row_norms_kernel<<<N, 256, 0, stream>>>(step, na);
    row_norms_kernel<<<M, 256, 0, stream>>>(modal, nb);
    row_norms_kernel<<<M, 256, 0, stream>>>(negs, nn);

    // 2. negatives GEMM into attention region (scratch), then row maxes
    dim3 grid(M / BN, N / BM);
    gemm_nt_kernel<<<grid, 256, 0, stream>>>(step, negs, attn, N, M, K);
    neg_rowmax_kernel<<<N, 256, 0, stream>>>(attn, na, nn, negmax, M);

    // 3. positives GEMM (overwrites scratch), fused softmax in place
    gemm_nt_kernel<<<grid, 256, 0, stream>>>(step, modal, attn, N, M, K);
    softmax_row_kernel<<<N, 256, 0, stream>>>(attn, na, nb, perstep, wsum, M);

    // 4. scalars
    finalize_kernel<<<1, 256, 0, stream>>>(perstep, wsum, negmax, out, N, NM);
}

// Round 2
// 562.335 us; speedup vs baseline: 3.0625x; 3.0625x over previous
//
#include <hip/hip_runtime.h>
#include <cmath>

// ---------------------------------------------------------------------------
// Round 2: bf16 MFMA GEMM for both dot matrices + fp32 exact fix-up of
// softmax top candidates. Cosine-derived outputs tolerate bf16 dot error
// (~5e-5 in cosine units); only near-max logits need fp32 accuracy.
// ---------------------------------------------------------------------------

#define WAVE 64

typedef __bf16 bf16x8_t __attribute__((ext_vector_type(8)));
typedef float f32x4_t __attribute__((ext_vector_type(4)));

__device__ __forceinline__ float wave_reduce_sum(float v) {
#pragma unroll
    for (int o = 32; o > 0; o >>= 1) v += __shfl_down(v, o, WAVE);
    return v;
}
__device__ __forceinline__ float wave_reduce_max(float v) {
#pragma unroll
    for (int o = 32; o > 0; o >>= 1) v = fmaxf(v, __shfl_down(v, o, WAVE));
    return v;
}
__device__ __forceinline__ float wave_reduce_min(float v) {
#pragma unroll
    for (int o = 32; o > 0; o >>= 1) v = fminf(v, __shfl_down(v, o, WAVE));
    return v;
}

// ---------------- row L2 norms: one block per row, D=1024, 256 threads -----
__global__ __launch_bounds__(256)
void row_norms_kernel(const float* __restrict__ x, float* __restrict__ nrm) {
    const int row = blockIdx.x;
    const float4 v = ((const float4*)(x + (size_t)row * 1024))[threadIdx.x];
    float s = v.x * v.x + v.y * v.y + v.z * v.z + v.w * v.w;
    s = wave_reduce_sum(s);
    __shared__ float red[4];
    const int lane = threadIdx.x & 63, w = threadIdx.x >> 6;
    if (lane == 0) red[w] = s;
    __syncthreads();
    if (threadIdx.x == 0) {
        float t = red[0] + red[1] + red[2] + red[3];
        nrm[row] = fmaxf(sqrtf(t), 1e-8f);
    }
}

// ---------------- bf16 MFMA NT GEMM: C[R x Cn] = A[R x K] * B[Cn x K]^T ----
// 128x128 tile, BK=32, 4 waves each computing 64x64 via 4x4 of 16x16x32.
// fp32 inputs converted to bf16 (RNE) during LDS staging.
#define BM 128
#define BN 128
#define BK 32
#define LDK 40   // padded K-stride (bf16 elems): 80B rows -> ~2-way banks (free)

__device__ __forceinline__ bf16x8_t pack_bf16x8(float4 a, float4 b) {
    bf16x8_t v;
    v[0] = (__bf16)a.x; v[1] = (__bf16)a.y; v[2] = (__bf16)a.z; v[3] = (__bf16)a.w;
    v[4] = (__bf16)b.x; v[5] = (__bf16)b.y; v[6] = (__bf16)b.z; v[7] = (__bf16)b.w;
    return v;
}

__global__ __launch_bounds__(256, 3)
void gemm_bf16_nt_kernel(const float* __restrict__ A, const float* __restrict__ B,
                         float* __restrict__ C, int R, int Cn, int K) {
    __shared__ alignas(16) __bf16 As[BM * LDK];
    __shared__ alignas(16) __bf16 Bs[BN * LDK];

    const int t  = threadIdx.x;
    const int bm = blockIdx.y * BM;
    const int bn = blockIdx.x * BN;

    // staging assignment: thread t covers row t>>1, k-halves (t&1)*16..+15
    const int srow = t >> 1;
    const int skb  = (t & 1) << 4;
    const float* Ag = A + (size_t)(bm + srow) * K + skb;
    const float* Bg = B + (size_t)(bn + srow) * K + skb;

    // compute assignment: wave w -> 64x64 quadrant
    const int w      = t >> 6;
    const int lane   = t & 63;
    const int lane16 = lane & 15;
    const int lq     = lane >> 4;          // 0..3
    const int wm     = (w & 1) * 64;
    const int wn     = (w >> 1) * 64;

    f32x4_t acc[4][4];
#pragma unroll
    for (int i = 0; i < 4; i++)
#pragma unroll
        for (int j = 0; j < 4; j++) acc[i][j] = (f32x4_t){0.f, 0.f, 0.f, 0.f};

    float4 ar0, ar1, ar2, ar3, br0, br1, br2, br3;
    ar0 = *(const float4*)(Ag + 0);  ar1 = *(const float4*)(Ag + 4);
    ar2 = *(const float4*)(Ag + 8);  ar3 = *(const float4*)(Ag + 12);
    br0 = *(const float4*)(Bg + 0);  br1 = *(const float4*)(Bg + 4);
    br2 = *(const float4*)(Bg + 8);  br3 = *(const float4*)(Bg + 12);

    for (int k0 = 0; k0 < K; k0 += BK) {
        __syncthreads();   // previous iteration done reading LDS
        *(bf16x8_t*)&As[srow * LDK + skb]     = pack_bf16x8(ar0, ar1);
        *(bf16x8_t*)&As[srow * LDK + skb + 8] = pack_bf16x8(ar2, ar3);
        *(bf16x8_t*)&Bs[srow * LDK + skb]     = pack_bf16x8(br0, br1);
        *(bf16x8_t*)&Bs[srow * LDK + skb + 8] = pack_bf16x8(br2, br3);
        __syncthreads();

        if (k0 + BK < K) {   // prefetch next tile into regs, overlaps MFMA
            const float* an = Ag + k0 + BK;
            const float* bn2 = Bg + k0 + BK;
            ar0 = *(const float4*)(an + 0);  ar1 = *(const float4*)(an + 4);
            ar2 = *(const float4*)(an + 8);  ar3 = *(const float4*)(an + 12);
            br0 = *(const float4*)(bn2 + 0); br1 = *(const float4*)(bn2 + 4);
            br2 = *(const float4*)(bn2 + 8); br3 = *(const float4*)(bn2 + 12);
        }

        bf16x8_t af[4], bf[4];
#pragma unroll
        for (int i = 0; i < 4; i++)
            af[i] = *(const bf16x8_t*)&As[(wm + i * 16 + lane16) * LDK + lq * 8];
#pragma unroll
        for (int j = 0; j < 4; j++)
            bf[j] = *(const bf16x8_t*)&Bs[(wn + j * 16 + lane16) * LDK + lq * 8];

#pragma unroll
        for (int i = 0; i < 4; i++)
#pragma unroll
            for (int j = 0; j < 4; j++)
                acc[i][j] = __builtin_amdgcn_mfma_f32_16x16x32_bf16(
                    af[i], bf[j], acc[i][j], 0, 0, 0);
    }

    // C/D layout (16x16x32): col = lane&15, row = (lane>>4)*4 + reg
#pragma unroll
    for (int i = 0; i < 4; i++) {
#pragma unroll
        for (int r = 0; r < 4; r++) {
            const int grow = bm + wm + i * 16 + lq * 4 + r;
            float* crow = C + (size_t)grow * Cn + bn + wn + lane16;
#pragma unroll
            for (int j = 0; j < 4; j++)
                crow[j * 16] = acc[i][j][r];
        }
    }
}

// ---------------- negatives: per-row max cosine from raw dots --------------
__global__ __launch_bounds__(256)
void neg_rowmax_kernel(const float* __restrict__ G, const float* __restrict__ na,
                       const float* __restrict__ nn, float* __restrict__ negmax,
                       int M) {
    const int row = blockIdx.x;
    const float* g = G + (size_t)row * M;
    __shared__ float ns[4096];
    for (int i = threadIdx.x; i < M; i += 256) ns[i] = nn[i];
    __syncthreads();
    float cmax = -3.4e38f;
    for (int j = threadIdx.x; j < M; j += 256)
        cmax = fmaxf(cmax, g[j] / ns[j]);
    cmax = wave_reduce_max(cmax);
    __shared__ float red[4];
    const int lane = threadIdx.x & 63, w = threadIdx.x >> 6;
    if (lane == 0) red[w] = cmax;
    __syncthreads();
    if (threadIdx.x == 0) {
        float m = fmaxf(fmaxf(red[0], red[1]), fmaxf(red[2], red[3]));
        negmax[row] = m / na[row];
    }
}

// ---------------- softmax with fp32 fix-up of near-max candidates ----------
// G holds bf16-accuracy dots; entries within CUT of row max are recomputed
// exactly (fp32) before the softmax. Non-candidates have attention < e^-26.
#define CUT 2.0f
#define MAXCAND 64

__global__ __launch_bounds__(256)
void softmax_fix_kernel(float* __restrict__ G, const float* __restrict__ step,
                        const float* __restrict__ modal,
                        const float* __restrict__ na, const float* __restrict__ nb,
                        float* __restrict__ perstep, float* __restrict__ wout,
                        int M, int K) {
    const int row = blockIdx.x;
    float* g = G + (size_t)row * M;
    const int tid = threadIdx.x;
    const int lane = tid & 63, wv = tid >> 6;

    __shared__ float ns[4096];
    __shared__ float srow_s[1024];
    __shared__ float red[8];
    __shared__ float bcast[2];
    __shared__ int   cand[MAXCAND];
    __shared__ float exact[MAXCAND];
    __shared__ int   cnt;

    if (tid == 0) cnt = 0;
    for (int i = tid; i < M; i += 256) ns[i] = nb[i];
    {
        const float4 sv = ((const float4*)(step + (size_t)row * K))[tid];
        ((float4*)srow_s)[tid] = sv;
    }
    __syncthreads();

    float vals[16];
    float dmax = -3.4e38f;
#pragma unroll
    for (int j = 0; j < 16; j++) {
        vals[j] = g[tid + j * 256];
        dmax = fmaxf(dmax, vals[j]);
    }
    // block-reduce dot max
    float wm = wave_reduce_max(dmax);
    if (lane == 0) red[wv] = wm;
    __syncthreads();
    if (tid == 0) bcast[0] = fmaxf(fmaxf(red[0], red[1]), fmaxf(red[2], red[3]));
    __syncthreads();
    const float m0 = bcast[0];

    // collect candidates within CUT of (bf16-accuracy) max
    const float thr = m0 - CUT;
#pragma unroll
    for (int j = 0; j < 16; j++) {
        if (vals[j] >= thr) {
            const int pos = atomicAdd(&cnt, 1);
            if (pos < MAXCAND) cand[pos] = tid + j * 256;
        }
    }
    __syncthreads();
    const int nc = min(cnt, MAXCAND);

    // exact fp32 dot for each candidate (block-cooperative)
    for (int i = 0; i < nc; i++) {
        const float* mrow = modal + (size_t)cand[i] * K;
        float p = 0.0f;
#pragma unroll
        for (int q = 0; q < 4; q++) {
            const int idx = tid + q * 256;
            p = fmaf(srow_s[idx], mrow[idx], p);
        }
        p = wave_reduce_sum(p);
        if (lane == 0) red[wv] = p;
        __syncthreads();
        if (tid == 0) exact[i] = red[0] + red[1] + red[2] + red[3];
        __syncthreads();
    }

    // substitute exact values
    for (int i = 0; i < nc; i++) {
        const int c = cand[i];
        if ((c & 255) == tid) vals[c >> 8] = exact[i];
    }

    // recompute max (dot) + cosine max with corrected values
    float dmax2 = -3.4e38f, cmax = -3.4e38f;
#pragma unroll
    for (int j = 0; j < 16; j++) {
        dmax2 = fmaxf(dmax2, vals[j]);
        cmax = fmaxf(cmax, vals[j] / ns[tid + j * 256]);
    }
    float wg = wave_reduce_max(dmax2);
    float wc = wave_reduce_max(cmax);
    if (lane == 0) { red[wv] = wg; red[4 + wv] = wc; }
    __syncthreads();
    if (tid == 0) {
        bcast[0] = fmaxf(fmaxf(red[0], red[1]), fmaxf(red[2], red[3]));
        bcast[1] = fmaxf(fmaxf(red[4], red[5]), fmaxf(red[6], red[7]));
    }
    __syncthreads();
    const float invT = 1.0f / 0.07f;
    const float mlog = bcast[0] * invT;
    const float cmaxAll = bcast[1];

    float evals[16];
    float lsum = 0.0f;
#pragma unroll
    for (int j = 0; j < 16; j++) {
        const float e = __expf(vals[j] * invT - mlog);
        evals[j] = e;
        lsum += e;
    }
    lsum = wave_reduce_sum(lsum);
    __syncthreads();
    if (lane == 0) red[wv] = lsum;
    __syncthreads();
    if (tid == 0) bcast[0] = red[0] + red[1] + red[2] + red[3];
    __syncthreads();
    const float invZ = 1.0f / bcast[0];

    float wacc = 0.0f;
#pragma unroll
    for (int j = 0; j < 16; j++) {
        const int c = tid + j * 256;
        const float a = evals[j] * invZ;
        g[c] = a;
        wacc += a * vals[j] / ns[c];
    }
    wacc = wave_reduce_sum(wacc);
    __syncthreads();
    if (lane == 0) red[wv] = wacc;
    __syncthreads();
    if (tid == 0) {
        const float inv_na = 1.0f / na[row];
        perstep[row] = cmaxAll * inv_na;
        wout[row] = (red[0] + red[1] + red[2] + red[3]) * inv_na;
    }
}

// ---------------- finalize scalars -----------------------------------------
__global__ __launch_bounds__(256)
void finalize_kernel(const float* __restrict__ perstep, const float* __restrict__ w,
                     const float* __restrict__ negmax, float* __restrict__ out,
                     int N, size_t NM) {
    float s_a = 0.0f, s_w = 0.0f, s_n = 0.0f, mn = 3.4e38f;
    for (int i = threadIdx.x; i < N; i += 256) {
        const float p = perstep[i];
        s_a += p;
        s_w += w[i];
        s_n += negmax[i];
        mn = fminf(mn, p);
    }
    s_a = wave_reduce_sum(s_a);
    s_w = wave_reduce_sum(s_w);
    s_n = wave_reduce_sum(s_n);
    mn  = wave_reduce_min(mn);
    __shared__ float red[16];
    const int lane = threadIdx.x & 63, wv = threadIdx.x >> 6;
    if (lane == 0) { red[wv] = s_a; red[4 + wv] = s_w; red[8 + wv] = s_n; red[12 + wv] = mn; }
    __syncthreads();
    if (threadIdx.x == 0) {
        const float inv = 1.0f / (float)N;
        const float alignment = (red[0] + red[1] + red[2] + red[3]) * inv;
        const float weighted  = (red[4] + red[5] + red[6] + red[7]) * inv;
        const float neg       = (red[8] + red[9] + red[10] + red[11]) * inv;
        const float minstep   = fminf(fminf(red[12], red[13]), fminf(red[14], red[15]));
        const float contrast  = alignment - neg;
        const float margin    = fmaxf(contrast - 0.2f, 0.0f);
        const float overall   = 0.7f * weighted + 0.3f * contrast;
        out[0] = alignment;
        out[1] = weighted;
        float* p = out + 2 + NM;
        p[0] = contrast;
        p[1] = margin;
        p[2] = alignment;   // positive_alignment
        p[3] = neg;
        p[4 + N] = minstep;
        p[5 + N] = overall;
    }
}

// ---------------------------------------------------------------------------
extern "C" void kernel_launch(void* const* d_in, const int* in_sizes, int n_in,
                              void* d_out, int out_size, void* d_ws, size_t ws_size,
                              hipStream_t stream) {
    const float* step  = (const float*)d_in[0];
    const float* modal = (const float*)d_in[1];
    const float* negs  = (const float*)d_in[2];
    float* out = (float*)d_out;

    const int K = 1024;
    const int N = in_sizes[0] / K;   // 8192 steps
    const int M = in_sizes[1] / K;   // 4096 modal
    const size_t NM = (size_t)N * (size_t)M;

    // workspace layout (floats)
    float* ws      = (float*)d_ws;
    float* na      = ws;                 // N
    float* nb      = na + N;             // M
    float* nn      = nb + M;             // M
    float* negmax  = nn + M;             // N
    float* wsum    = negmax + N;         // N

    float* attn    = out + 2;            // attention region, also GEMM scratch
    float* perstep = out + 2 + NM + 4;   // per_step output slot

    // 1. norms
    row_norms_kernel<<<N, 256, 0, stream>>>(step, na);
    row_norms_kernel<<<M, 256, 0, stream>>>(modal, nb);
    row_norms_kernel<<<M, 256, 0, stream>>>(negs, nn);

    // 2. negatives GEMM (bf16 MFMA) into attention region, then row maxes
    dim3 grid(M / BN, N / BM);
    gemm_bf16_nt_kernel<<<grid, 256, 0, stream>>>(step, negs, attn, N, M, K);
    neg_rowmax_kernel<<<N, 256, 0, stream>>>(attn, na, nn, negmax, M);

    // 3. positives GEMM (overwrites scratch), softmax + exact fix-up in place
    gemm_bf16_nt_kernel<<<grid, 256, 0, stream>>>(step, modal, attn, N, M, K);
    softmax_fix_kernel<<<N, 256, 0, stream>>>(attn, step, modal, na, nb,
                                              perstep, wsum, M, K);

    // 4. scalars
    finalize_kernel<<<1, 256, 0, stream>>>(perstep, wsum, negmax, out, N, NM);
}

// Round 3
// 461.407 us; speedup vs baseline: 3.7323x; 1.2187x over previous
//
#include <hip/hip_runtime.h>
#include <cmath>

// ---------------------------------------------------------------------------
// Round 3: m97-style bf16 GEMM (global_load_lds width=16, pre-converted bf16
// inputs) + fused epilogues. Arena inside the attention output region:
//   slot r (16 KB) = [ G-bf16 row r : 8 KB | input bf16 chunks : 8 KB ]
// neg GEMM: no C store, per-row cosine max via atomicMax (ordered-uint map).
// pos GEMM: stores G as bf16 (halves traffic); softmax does fp32 fix-up of
// near-max candidates, writes fp32 attention over its own slot.
// ---------------------------------------------------------------------------

#define WAVE 64

typedef __bf16 bf16x8_t __attribute__((ext_vector_type(8)));
typedef __bf16 bf16x4_t __attribute__((ext_vector_type(4)));
typedef float f32x4_t __attribute__((ext_vector_type(4)));

__device__ __forceinline__ float wave_reduce_sum(float v) {
#pragma unroll
    for (int o = 32; o > 0; o >>= 1) v += __shfl_down(v, o, WAVE);
    return v;
}
__device__ __forceinline__ float wave_reduce_max(float v) {
#pragma unroll
    for (int o = 32; o > 0; o >>= 1) v = fmaxf(v, __shfl_down(v, o, WAVE));
    return v;
}
__device__ __forceinline__ float wave_reduce_min(float v) {
#pragma unroll
    for (int o = 32; o > 0; o >>= 1) v = fminf(v, __shfl_down(v, o, WAVE));
    return v;
}

// monotone float <-> uint map for atomicMax on floats of any sign
__device__ __forceinline__ unsigned enc_f(float f) {
    unsigned u = __float_as_uint(f);
    return (u & 0x80000000u) ? ~u : (u | 0x80000000u);
}
__device__ __forceinline__ float dec_f(unsigned e) {
    unsigned u = (e & 0x80000000u) ? (e & 0x7fffffffu) : ~e;
    return __uint_as_float(u);
}

// input bf16 chunk c (one 1024-elem row, 2 KB) lives in the BACK half of
// slot (c>>2), sub-position (c&3).
__device__ __forceinline__ const __bf16* chunk_ptr(const char* arena, int c) {
    return (const __bf16*)(arena + (((size_t)(c >> 2)) << 14) +
                           ((size_t)(c & 3) << 11) + 8192);
}

// ---------------- convert fp32 -> bf16 chunks + inverse norms --------------
// grid = N + M + M blocks (one per source row), 256 threads.
__global__ __launch_bounds__(256)
void convert_norms_kernel(const float* __restrict__ step,
                          const float* __restrict__ modal,
                          const float* __restrict__ negs,
                          char* __restrict__ arena,
                          float* __restrict__ ina, float* __restrict__ inb,
                          float* __restrict__ inn,
                          unsigned* __restrict__ negmax_u, int N, int M) {
    const int b = blockIdx.x, tid = threadIdx.x;
    const float* src;
    if (b < N)          src = step  + (size_t)b * 1024;
    else if (b < N + M) src = modal + (size_t)(b - N) * 1024;
    else                src = negs  + (size_t)(b - N - M) * 1024;

    const float4 v = ((const float4*)src)[tid];
    // write bf16 chunk
    char* cb = arena + (((size_t)(b >> 2)) << 14) + ((size_t)(b & 3) << 11) + 8192;
    bf16x4_t o;
    o[0] = (__bf16)v.x; o[1] = (__bf16)v.y; o[2] = (__bf16)v.z; o[3] = (__bf16)v.w;
    *(bf16x4_t*)(cb + (size_t)tid * 8) = o;

    float s = v.x * v.x + v.y * v.y + v.z * v.z + v.w * v.w;
    s = wave_reduce_sum(s);
    __shared__ float red[4];
    const int lane = tid & 63, w = tid >> 6;
    if (lane == 0) red[w] = s;
    __syncthreads();
    if (tid == 0) {
        const float nrm = fmaxf(sqrtf(red[0] + red[1] + red[2] + red[3]), 1e-8f);
        const float inv = 1.0f / nrm;
        if (b < N)          { ina[b] = inv; negmax_u[b] = 0u; }
        else if (b < N + M) inb[b - N] = inv;
        else                inn[b - N - M] = inv;
    }
}

// ---------------- bf16 MFMA GEMM over arena chunks -------------------------
// 128x128 tile, BK=32, global_load_lds width=16 staging (m97 structure).
// mode 0: negatives — no C store, atomic per-row cosine max.
// mode 1: positives — store G as bf16 into slot front halves.
#define GLD16(g, l)                                                        \
    __builtin_amdgcn_global_load_lds(                                     \
        (const __attribute__((address_space(1))) void*)(g),               \
        (__attribute__((address_space(3))) void*)(l), 16, 0, 0)

__global__ __launch_bounds__(256, 4)
void gemm_arena_kernel(char* __restrict__ arena, int a_chunk0, int b_chunk0,
                       int mode, const float* __restrict__ inv_nn,
                       unsigned* __restrict__ negmax_u) {
    __shared__ __bf16 As[128 * 32];
    __shared__ __bf16 Bs[128 * 32];

    const int t = threadIdx.x, w = t >> 6, lane = t & 63;
    const int bm = blockIdx.y * 128, bn = blockIdx.x * 128;
    const int lane16 = lane & 15, lq = lane >> 4;
    const int wm = (w & 1) * 64, wn = (w >> 1) * 64;

    // staging: wave w covers tile rows w*32 .. w*32+31, two 16-row segments.
    // lane -> row = seg*16 + lane/4, k-chunk = (lane&3)*8 bf16 (16 B).
    const int srow  = lane >> 2;
    const int skoff = (lane & 3) * 8;
    const __bf16* ga[2]; const __bf16* gb[2];
    __bf16* lA[2]; __bf16* lB[2];
#pragma unroll
    for (int seg = 0; seg < 2; seg++) {
        const int ra = w * 32 + seg * 16 + srow;
        ga[seg] = chunk_ptr(arena, a_chunk0 + bm + ra) + skoff;
        gb[seg] = chunk_ptr(arena, b_chunk0 + bn + ra) + skoff;
        lA[seg] = &As[(w * 32 + seg * 16) * 32];
        lB[seg] = &Bs[(w * 32 + seg * 16) * 32];
    }

    f32x4_t acc[4][4];
#pragma unroll
    for (int i = 0; i < 4; i++)
#pragma unroll
        for (int j = 0; j < 4; j++) acc[i][j] = (f32x4_t){0.f, 0.f, 0.f, 0.f};

    for (int k0 = 0; k0 < 1024; k0 += 32) {
        __syncthreads();   // all waves done reading LDS from prev iter
#pragma unroll
        for (int seg = 0; seg < 2; seg++) {
            GLD16(ga[seg] + k0, lA[seg]);
            GLD16(gb[seg] + k0, lB[seg]);
        }
        __syncthreads();   // compiler drains vmcnt before s_barrier

        bf16x8_t af[4], bf[4];
#pragma unroll
        for (int i = 0; i < 4; i++)
            af[i] = *(const bf16x8_t*)&As[(wm + i * 16 + lane16) * 32 + lq * 8];
#pragma unroll
        for (int j = 0; j < 4; j++)
            bf[j] = *(const bf16x8_t*)&Bs[(wn + j * 16 + lane16) * 32 + lq * 8];

#pragma unroll
        for (int i = 0; i < 4; i++)
#pragma unroll
            for (int j = 0; j < 4; j++)
                acc[i][j] = __builtin_amdgcn_mfma_f32_16x16x32_bf16(
                    af[i], bf[j], acc[i][j], 0, 0, 0);
    }

    // C/D layout (16x16x32): col = lane16, row = lq*4 + reg
    if (mode == 0) {
        // negatives: per-row max of dot * inv_nn[col], atomicMax per row
        float invn[4];
#pragma unroll
        for (int j = 0; j < 4; j++)
            invn[j] = inv_nn[bn + wn + j * 16 + lane16];
#pragma unroll
        for (int i = 0; i < 4; i++) {
#pragma unroll
            for (int r = 0; r < 4; r++) {
                float v = acc[i][0][r] * invn[0];
                v = fmaxf(v, acc[i][1][r] * invn[1]);
                v = fmaxf(v, acc[i][2][r] * invn[2]);
                v = fmaxf(v, acc[i][3][r] * invn[3]);
                // reduce across the 16 lanes sharing this row (same lq)
#pragma unroll
                for (int o = 8; o > 0; o >>= 1)
                    v = fmaxf(v, __shfl_xor(v, o, WAVE));
                if (lane16 == 0)
                    atomicMax(&negmax_u[bm + wm + i * 16 + lq * 4 + r], enc_f(v));
            }
        }
    } else {
        // positives: store G as bf16 into slot front halves
#pragma unroll
        for (int i = 0; i < 4; i++) {
#pragma unroll
            for (int r = 0; r < 4; r++) {
                const int grow = bm + wm + i * 16 + lq * 4 + r;
                __bf16* dst = (__bf16*)(arena + ((size_t)grow << 14)) +
                              bn + wn + lane16;
#pragma unroll
                for (int j = 0; j < 4; j++)
                    dst[j * 16] = (__bf16)acc[i][j][r];
            }
        }
    }
}

// ---------------- softmax with fp32 fix-up, bf16 G -> fp32 attention -------
#define CUT 2.0f
#define MAXCAND 64

__global__ __launch_bounds__(256)
void softmax_fix_kernel(char* __restrict__ arena, const float* __restrict__ step,
                        const float* __restrict__ modal,
                        const float* __restrict__ ina, const float* __restrict__ inb,
                        float* __restrict__ perstep, float* __restrict__ wout,
                        float* __restrict__ attn) {
    const int row = blockIdx.x, tid = threadIdx.x;
    const int lane = tid & 63, wv = tid >> 6;

    __shared__ float srow_s[1024];
    __shared__ float red[8];
    __shared__ float bcast[2];
    __shared__ int   cand[MAXCAND];
    __shared__ float exact[MAXCAND];
    __shared__ int   cnt;

    if (tid == 0) cnt = 0;
    ((float4*)srow_s)[tid] = ((const float4*)(step + (size_t)row * 1024))[tid];

    // thread tid owns cols tid*16 .. tid*16+15 (contiguous bf16 + float4 IO)
    const __bf16* gb = (const __bf16*)(arena + ((size_t)row << 14)) + tid * 16;
    float vals[16];
    {
        bf16x8_t v0 = *(const bf16x8_t*)gb;
        bf16x8_t v1 = *(const bf16x8_t*)(gb + 8);
#pragma unroll
        for (int j = 0; j < 8; j++) { vals[j] = (float)v0[j]; vals[8 + j] = (float)v1[j]; }
    }
    float invn[16];
    {
        const float4* p = (const float4*)(inb + tid * 16);
#pragma unroll
        for (int q = 0; q < 4; q++) {
            const float4 x = p[q];
            invn[q * 4 + 0] = x.x; invn[q * 4 + 1] = x.y;
            invn[q * 4 + 2] = x.z; invn[q * 4 + 3] = x.w;
        }
    }

    float dmax = -3.4e38f;
#pragma unroll
    for (int j = 0; j < 16; j++) dmax = fmaxf(dmax, vals[j]);
    float wm = wave_reduce_max(dmax);
    if (lane == 0) red[wv] = wm;
    __syncthreads();   // also covers cnt=0 and srow_s
    if (tid == 0) bcast[0] = fmaxf(fmaxf(red[0], red[1]), fmaxf(red[2], red[3]));
    __syncthreads();
    const float m0 = bcast[0];

    // collect candidates within CUT of the (bf16-accuracy) max
    const float thr = m0 - CUT;
#pragma unroll
    for (int j = 0; j < 16; j++) {
        if (vals[j] >= thr) {
            const int pos = atomicAdd(&cnt, 1);
            if (pos < MAXCAND) cand[pos] = tid * 16 + j;
        }
    }
    __syncthreads();
    const int nc = min(cnt, MAXCAND);

    // exact fp32 dot per candidate (block-cooperative)
    for (int i = 0; i < nc; i++) {
        const float* mrow = modal + (size_t)cand[i] * 1024;
        float p = 0.0f;
#pragma unroll
        for (int q = 0; q < 4; q++) {
            const int idx = tid + q * 256;
            p = fmaf(srow_s[idx], mrow[idx], p);
        }
        p = wave_reduce_sum(p);
        if (lane == 0) red[wv] = p;
        __syncthreads();
        if (tid == 0) exact[i] = red[0] + red[1] + red[2] + red[3];
        __syncthreads();
    }

    // substitute exact values
    for (int i = 0; i < nc; i++) {
        const int c = cand[i];
        if ((c >> 4) == tid) vals[c & 15] = exact[i];
    }

    // corrected dot max + cosine max
    float dmax2 = -3.4e38f, cmax = -3.4e38f;
#pragma unroll
    for (int j = 0; j < 16; j++) {
        dmax2 = fmaxf(dmax2, vals[j]);
        cmax = fmaxf(cmax, vals[j] * invn[j]);
    }
    float wg = wave_reduce_max(dmax2);
    float wc = wave_reduce_max(cmax);
    if (lane == 0) { red[wv] = wg; red[4 + wv] = wc; }
    __syncthreads();
    if (tid == 0) {
        bcast[0] = fmaxf(fmaxf(red[0], red[1]), fmaxf(red[2], red[3]));
        bcast[1] = fmaxf(fmaxf(red[4], red[5]), fmaxf(red[6], red[7]));
    }
    __syncthreads();
    const float invT = 1.0f / 0.07f;
    const float mlog = bcast[0] * invT;
    const float cmaxAll = bcast[1];

    float evals[16];
    float lsum = 0.0f;
#pragma unroll
    for (int j = 0; j < 16; j++) {
        const float e = __expf(vals[j] * invT - mlog);
        evals[j] = e;
        lsum += e;
    }
    lsum = wave_reduce_sum(lsum);
    __syncthreads();
    if (lane == 0) red[wv] = lsum;
    __syncthreads();
    if (tid == 0) bcast[0] = red[0] + red[1] + red[2] + red[3];
    __syncthreads();
    const float invZ = 1.0f / bcast[0];

    // write fp32 attention (overwrites own slot; all vals already in regs)
    float* g32 = attn + (size_t)row * 4096 + tid * 16;
    float wacc = 0.0f;
#pragma unroll
    for (int q = 0; q < 4; q++) {
        float4 o;
        float a0 = evals[q * 4 + 0] * invZ, a1 = evals[q * 4 + 1] * invZ;
        float a2 = evals[q * 4 + 2] * invZ, a3 = evals[q * 4 + 3] * invZ;
        o.x = a0; o.y = a1; o.z = a2; o.w = a3;
        ((float4*)g32)[q] = o;
        wacc += a0 * vals[q * 4 + 0] * invn[q * 4 + 0];
        wacc += a1 * vals[q * 4 + 1] * invn[q * 4 + 1];
        wacc += a2 * vals[q * 4 + 2] * invn[q * 4 + 2];
        wacc += a3 * vals[q * 4 + 3] * invn[q * 4 + 3];
    }
    wacc = wave_reduce_sum(wacc);
    __syncthreads();
    if (lane == 0) red[wv] = wacc;
    __syncthreads();
    if (tid == 0) {
        const float inv_na = ina[row];
        perstep[row] = cmaxAll * inv_na;
        wout[row] = (red[0] + red[1] + red[2] + red[3]) * inv_na;
    }
}

// ---------------- finalize scalars -----------------------------------------
__global__ __launch_bounds__(256)
void finalize_kernel(const float* __restrict__ perstep, const float* __restrict__ w,
                     const unsigned* __restrict__ negmax_u,
                     const float* __restrict__ ina, float* __restrict__ out,
                     int N, size_t NM) {
    float s_a = 0.0f, s_w = 0.0f, s_n = 0.0f, mn = 3.4e38f;
    for (int i = threadIdx.x; i < N; i += 256) {
        const float p = perstep[i];
        s_a += p;
        s_w += w[i];
        s_n += dec_f(negmax_u[i]) * ina[i];
        mn = fminf(mn, p);
    }
    s_a = wave_reduce_sum(s_a);
    s_w = wave_reduce_sum(s_w);
    s_n = wave_reduce_sum(s_n);
    mn  = wave_reduce_min(mn);
    __shared__ float red[16];
    const int lane = threadIdx.x & 63, wv = threadIdx.x >> 6;
    if (lane == 0) { red[wv] = s_a; red[4 + wv] = s_w; red[8 + wv] = s_n; red[12 + wv] = mn; }
    __syncthreads();
    if (threadIdx.x == 0) {
        const float inv = 1.0f / (float)N;
        const float alignment = (red[0] + red[1] + red[2] + red[3]) * inv;
        const float weighted  = (red[4] + red[5] + red[6] + red[7]) * inv;
        const float neg       = (red[8] + red[9] + red[10] + red[11]) * inv;
        const float minstep   = fminf(fminf(red[12], red[13]), fminf(red[14], red[15]));
        const float contrast  = alignment - neg;
        const float margin    = fmaxf(contrast - 0.2f, 0.0f);
        const float overall   = 0.7f * weighted + 0.3f * contrast;
        out[0] = alignment;
        out[1] = weighted;
        float* p = out + 2 + NM;
        p[0] = contrast;
        p[1] = margin;
        p[2] = alignment;   // positive_alignment
        p[3] = neg;
        p[4 + N] = minstep;
        p[5 + N] = overall;
    }
}

// ---------------------------------------------------------------------------
extern "C" void kernel_launch(void* const* d_in, const int* in_sizes, int n_in,
                              void* d_out, int out_size, void* d_ws, size_t ws_size,
                              hipStream_t stream) {
    const float* step  = (const float*)d_in[0];
    const float* modal = (const float*)d_in[1];
    const float* negs  = (const float*)d_in[2];
    float* out = (float*)d_out;

    const int K = 1024;
    const int N = in_sizes[0] / K;   // 8192
    const int M = in_sizes[1] / K;   // 4096
    const size_t NM = (size_t)N * (size_t)M;

    // small scalars in ws
    float* ina        = (float*)d_ws;          // N
    float* inb        = ina + N;               // M
    float* inn        = inb + M;               // M
    unsigned* negmax  = (unsigned*)(inn + M);  // N
    float* wsum       = (float*)(negmax + N);  // N

    char* arena    = (char*)d_out + 16;        // 16B-aligned slot arena
    float* attn    = out + 2;
    float* perstep = out + 2 + NM + 4;

    // 1. convert inputs to bf16 chunks + inverse norms + init atomics
    convert_norms_kernel<<<N + 2 * M, 256, 0, stream>>>(
        step, modal, negs, arena, ina, inb, inn, negmax, N, M);

    // 2. negatives GEMM: atomic per-row cosine max, no C store
    dim3 grid(M / 128, N / 128);
    gemm_arena_kernel<<<grid, 256, 0, stream>>>(arena, 0, N + M, 0, inn, negmax);

    // 3. positives GEMM: G (bf16) into slot front halves
    gemm_arena_kernel<<<grid, 256, 0, stream>>>(arena, 0, N, 1, inn, negmax);

    // 4. softmax + exact fp32 fix-up, writes fp32 attention + per-row outs
    softmax_fix_kernel<<<N, 256, 0, stream>>>(arena, step, modal, ina, inb,
                                              perstep, wsum, attn);

    // 5. scalars
    finalize_kernel<<<1, 256, 0, stream>>>(perstep, wsum, negmax, ina, out, N, NM);
}

// Round 4
// 428.452 us; speedup vs baseline: 4.0194x; 1.0769x over previous
//
#include <hip/hip_runtime.h>
#include <cmath>

// ---------------------------------------------------------------------------
// Round 4: single fused GEMM (B = modal ⊕ negs), BK=64 (half the barrier
// drains, 32 KB LDS keeps 4 blocks/CU), XOR-swizzled LDS layout
// (octet' = octet ^ (row&7)) so GLD16 staging stays linear but fragment
// ds_read_b128s spread evenly over bank groups (2-way = free).
// Arena (inside attention output region): slot r (16 KB) =
//   [ G-bf16 row r : 8 KB | input bf16 chunks 4r..4r+3 : 8 KB ]
// chunk order: 0..N-1 step, N..N+M-1 modal, N+M..N+2M-1 negs.
// ---------------------------------------------------------------------------

#define WAVE 64

typedef __bf16 bf16x8_t __attribute__((ext_vector_type(8)));
typedef __bf16 bf16x4_t __attribute__((ext_vector_type(4)));
typedef float f32x4_t __attribute__((ext_vector_type(4)));

__device__ __forceinline__ float wave_reduce_sum(float v) {
#pragma unroll
    for (int o = 32; o > 0; o >>= 1) v += __shfl_down(v, o, WAVE);
    return v;
}
__device__ __forceinline__ float wave_reduce_max(float v) {
#pragma unroll
    for (int o = 32; o > 0; o >>= 1) v = fmaxf(v, __shfl_down(v, o, WAVE));
    return v;
}
__device__ __forceinline__ float wave_reduce_min(float v) {
#pragma unroll
    for (int o = 32; o > 0; o >>= 1) v = fminf(v, __shfl_down(v, o, WAVE));
    return v;
}

// monotone float <-> uint map for atomicMax on floats of any sign
__device__ __forceinline__ unsigned enc_f(float f) {
    unsigned u = __float_as_uint(f);
    return (u & 0x80000000u) ? ~u : (u | 0x80000000u);
}
__device__ __forceinline__ float dec_f(unsigned e) {
    unsigned u = (e & 0x80000000u) ? (e & 0x7fffffffu) : ~e;
    return __uint_as_float(u);
}

// ---------------- convert fp32 -> bf16 chunks + inverse norms --------------
__global__ __launch_bounds__(256)
void convert_norms_kernel(const float* __restrict__ step,
                          const float* __restrict__ modal,
                          const float* __restrict__ negs,
                          char* __restrict__ arena,
                          float* __restrict__ ina, float* __restrict__ inb,
                          float* __restrict__ inn,
                          unsigned* __restrict__ negmax_u, int N, int M) {
    const int b = blockIdx.x, tid = threadIdx.x;
    const float* src;
    if (b < N)          src = step  + (size_t)b * 1024;
    else if (b < N + M) src = modal + (size_t)(b - N) * 1024;
    else                src = negs  + (size_t)(b - N - M) * 1024;

    const float4 v = ((const float4*)src)[tid];
    char* cb = arena + (((size_t)(b >> 2)) << 14) + ((size_t)(b & 3) << 11) + 8192;
    bf16x4_t o;
    o[0] = (__bf16)v.x; o[1] = (__bf16)v.y; o[2] = (__bf16)v.z; o[3] = (__bf16)v.w;
    *(bf16x4_t*)(cb + (size_t)tid * 8) = o;

    float s = v.x * v.x + v.y * v.y + v.z * v.z + v.w * v.w;
    s = wave_reduce_sum(s);
    __shared__ float red[4];
    const int lane = tid & 63, w = tid >> 6;
    if (lane == 0) red[w] = s;
    __syncthreads();
    if (tid == 0) {
        const float nrm = fmaxf(sqrtf(red[0] + red[1] + red[2] + red[3]), 1e-8f);
        const float inv = 1.0f / nrm;
        if (b < N)          { ina[b] = inv; negmax_u[b] = 0u; }
        else if (b < N + M) inb[b - N] = inv;
        else                inn[b - N - M] = inv;
    }
}

// ---------------- fused bf16 MFMA GEMM over arena chunks -------------------
// grid = (2M/128, N/128). blockIdx.x < M/128 -> modal (store G bf16);
// else -> negatives (atomic per-row cosine max, no store).
#define GLD16(g, l)                                                        \
    __builtin_amdgcn_global_load_lds(                                     \
        (const __attribute__((address_space(1))) void*)(g),               \
        (__attribute__((address_space(3))) void*)(l), 16, 0, 0)

__global__ __launch_bounds__(256, 4)
void gemm_fused_kernel(char* __restrict__ arena, int N, int M,
                       const float* __restrict__ inv_nn,
                       unsigned* __restrict__ negmax_u) {
    __shared__ __bf16 As[128 * 64];   // 16 KB, row-major, 64 bf16 per row
    __shared__ __bf16 Bs[128 * 64];   // 16 KB

    const int t = threadIdx.x, w = t >> 6, lane = t & 63;
    const int bm = blockIdx.y * 128, bn = blockIdx.x * 128;
    const int lane16 = lane & 15, lq = lane >> 4;
    const int wm = (w & 1) * 64, wn = (w >> 1) * 64;

    // ---- staging assignment: waves 0-1 -> As halves, waves 2-3 -> Bs ----
    // chunk c = r*64 + lane; row = r*8 + (lane>>3); lds octet = lane&7;
    // global octet = (lane&7) ^ (row&7) = (lane&7) ^ (lane>>3)   [swizzle]
    const int s_is_b  = w >> 1;
    const int rowbase = (w & 1) * 64;
    const int ln3 = lane >> 3;
    const int q_g = (lane & 7) ^ ln3;
    const int cbase = (s_is_b ? (N + bn) : bm) + rowbase;
    const int cc = cbase + ln3;      // chunk index for r=0
    // chunk c -> byte offset: (c>>2)<<14 | (c&3)<<11 | +8192; c+8r -> +r*32768
    const size_t off0 = (((size_t)(cc >> 2)) << 14) +
                        ((size_t)(cc & 3) << 11) + 8192 + (size_t)q_g * 16;
    const char* gbase = arena + off0;
    __bf16* ldsw = (s_is_b ? Bs : As) + rowbase * 64;

    f32x4_t acc[4][4];
#pragma unroll
    for (int i = 0; i < 4; i++)
#pragma unroll
        for (int j = 0; j < 4; j++) acc[i][j] = (f32x4_t){0.f, 0.f, 0.f, 0.f};

    const int sxr = lane16 & 7;      // row&7 for all fragment rows

    for (int k0b = 0; k0b < 2048; k0b += 128) {   // byte offset along K
        __syncthreads();   // all waves done reading LDS from prev iter
#pragma unroll
        for (int r = 0; r < 8; r++)
            GLD16(gbase + (size_t)r * 32768 + k0b, ldsw + r * 512);
        __syncthreads();   // vmcnt drained before barrier (compiler-enforced)

#pragma unroll
        for (int kk = 0; kk < 2; kk++) {
            const int qo = ((lq + kk * 4) ^ sxr) * 8;   // swizzled octet
            bf16x8_t af[4], bf[4];
#pragma unroll
            for (int i = 0; i < 4; i++)
                af[i] = *(const bf16x8_t*)&As[(wm + i * 16 + lane16) * 64 + qo];
#pragma unroll
            for (int j = 0; j < 4; j++)
                bf[j] = *(const bf16x8_t*)&Bs[(wn + j * 16 + lane16) * 64 + qo];
#pragma unroll
            for (int i = 0; i < 4; i++)
#pragma unroll
                for (int j = 0; j < 4; j++)
                    acc[i][j] = __builtin_amdgcn_mfma_f32_16x16x32_bf16(
                        af[i], bf[j], acc[i][j], 0, 0, 0);
        }
    }

    // C/D layout (16x16x32): col = lane16, row = lq*4 + reg
    if (bn < M) {
        // modal half: store G as bf16 into slot front halves
#pragma unroll
        for (int i = 0; i < 4; i++) {
#pragma unroll
            for (int r = 0; r < 4; r++) {
                const int grow = bm + wm + i * 16 + lq * 4 + r;
                __bf16* dst = (__bf16*)(arena + ((size_t)grow << 14)) +
                              bn + wn + lane16;
#pragma unroll
                for (int j = 0; j < 4; j++)
                    dst[j * 16] = (__bf16)acc[i][j][r];
            }
        }
    } else {
        // negatives half: per-row max of dot * inv_nn[col], atomicMax per row
        float invn[4];
#pragma unroll
        for (int j = 0; j < 4; j++)
            invn[j] = inv_nn[(bn - M) + wn + j * 16 + lane16];
#pragma unroll
        for (int i = 0; i < 4; i++) {
#pragma unroll
            for (int r = 0; r < 4; r++) {
                float v = acc[i][0][r] * invn[0];
                v = fmaxf(v, acc[i][1][r] * invn[1]);
                v = fmaxf(v, acc[i][2][r] * invn[2]);
                v = fmaxf(v, acc[i][3][r] * invn[3]);
#pragma unroll
                for (int o = 8; o > 0; o >>= 1)
                    v = fmaxf(v, __shfl_xor(v, o, WAVE));
                if (lane16 == 0)
                    atomicMax(&negmax_u[bm + wm + i * 16 + lq * 4 + r], enc_f(v));
            }
        }
    }
}

// ---------------- softmax with fp32 fix-up, bf16 G -> fp32 attention -------
#define CUT 2.0f
#define MAXCAND 64

__global__ __launch_bounds__(256)
void softmax_fix_kernel(char* __restrict__ arena, const float* __restrict__ step,
                        const float* __restrict__ modal,
                        const float* __restrict__ ina, const float* __restrict__ inb,
                        float* __restrict__ perstep, float* __restrict__ wout,
                        float* __restrict__ attn) {
    const int row = blockIdx.x, tid = threadIdx.x;
    const int lane = tid & 63, wv = tid >> 6;

    __shared__ float srow_s[1024];
    __shared__ float red[8];
    __shared__ float bcast[2];
    __shared__ int   cand[MAXCAND];
    __shared__ float exact[MAXCAND];
    __shared__ int   cnt;

    if (tid == 0) cnt = 0;
    ((float4*)srow_s)[tid] = ((const float4*)(step + (size_t)row * 1024))[tid];

    // thread tid owns cols tid*16 .. tid*16+15
    const __bf16* gb = (const __bf16*)(arena + ((size_t)row << 14)) + tid * 16;
    float vals[16];
    {
        bf16x8_t v0 = *(const bf16x8_t*)gb;
        bf16x8_t v1 = *(const bf16x8_t*)(gb + 8);
#pragma unroll
        for (int j = 0; j < 8; j++) { vals[j] = (float)v0[j]; vals[8 + j] = (float)v1[j]; }
    }
    float invn[16];
    {
        const float4* p = (const float4*)(inb + tid * 16);
#pragma unroll
        for (int q = 0; q < 4; q++) {
            const float4 x = p[q];
            invn[q * 4 + 0] = x.x; invn[q * 4 + 1] = x.y;
            invn[q * 4 + 2] = x.z; invn[q * 4 + 3] = x.w;
        }
    }

    float dmax = -3.4e38f;
#pragma unroll
    for (int j = 0; j < 16; j++) dmax = fmaxf(dmax, vals[j]);
    float wm = wave_reduce_max(dmax);
    if (lane == 0) red[wv] = wm;
    __syncthreads();   // also covers cnt=0 and srow_s
    if (tid == 0) bcast[0] = fmaxf(fmaxf(red[0], red[1]), fmaxf(red[2], red[3]));
    __syncthreads();
    const float m0 = bcast[0];

    // collect candidates within CUT of the (bf16-accuracy) max
    const float thr = m0 - CUT;
#pragma unroll
    for (int j = 0; j < 16; j++) {
        if (vals[j] >= thr) {
            const int pos = atomicAdd(&cnt, 1);
            if (pos < MAXCAND) cand[pos] = tid * 16 + j;
        }
    }
    __syncthreads();
    const int nc = min(cnt, MAXCAND);

    // exact fp32 dots, one candidate per wave (no block barriers inside)
    for (int i = wv; i < nc; i += 4) {
        const float* mrow = modal + (size_t)cand[i] * 1024;
        float p = 0.0f;
#pragma unroll
        for (int q = 0; q < 16; q++) {
            const int idx = lane + q * 64;
            p = fmaf(srow_s[idx], mrow[idx], p);
        }
        p = wave_reduce_sum(p);
        if (lane == 0) exact[i] = p;
    }
    __syncthreads();

    // substitute exact values
    for (int i = 0; i < nc; i++) {
        const int c = cand[i];
        if ((c >> 4) == tid) vals[c & 15] = exact[i];
    }

    // corrected dot max + cosine max
    float dmax2 = -3.4e38f, cmax = -3.4e38f;
#pragma unroll
    for (int j = 0; j < 16; j++) {
        dmax2 = fmaxf(dmax2, vals[j]);
        cmax = fmaxf(cmax, vals[j] * invn[j]);
    }
    float wg = wave_reduce_max(dmax2);
    float wc = wave_reduce_max(cmax);
    if (lane == 0) { red[wv] = wg; red[4 + wv] = wc; }
    __syncthreads();
    if (tid == 0) {
        bcast[0] = fmaxf(fmaxf(red[0], red[1]), fmaxf(red[2], red[3]));
        bcast[1] = fmaxf(fmaxf(red[4], red[5]), fmaxf(red[6], red[7]));
    }
    __syncthreads();
    const float invT = 1.0f / 0.07f;
    const float mlog = bcast[0] * invT;
    const float cmaxAll = bcast[1];

    float evals[16];
    float lsum = 0.0f;
#pragma unroll
    for (int j = 0; j < 16; j++) {
        const float e = __expf(vals[j] * invT - mlog);
        evals[j] = e;
        lsum += e;
    }
    lsum = wave_reduce_sum(lsum);
    __syncthreads();
    if (lane == 0) red[wv] = lsum;
    __syncthreads();
    if (tid == 0) bcast[0] = red[0] + red[1] + red[2] + red[3];
    __syncthreads();
    const float invZ = 1.0f / bcast[0];

    float* g32 = attn + (size_t)row * 4096 + tid * 16;
    float wacc = 0.0f;
#pragma unroll
    for (int q = 0; q < 4; q++) {
        float4 o;
        float a0 = evals[q * 4 + 0] * invZ, a1 = evals[q * 4 + 1] * invZ;
        float a2 = evals[q * 4 + 2] * invZ, a3 = evals[q * 4 + 3] * invZ;
        o.x = a0; o.y = a1; o.z = a2; o.w = a3;
        ((float4*)g32)[q] = o;
        wacc += a0 * vals[q * 4 + 0] * invn[q * 4 + 0];
        wacc += a1 * vals[q * 4 + 1] * invn[q * 4 + 1];
        wacc += a2 * vals[q * 4 + 2] * invn[q * 4 + 2];
        wacc += a3 * vals[q * 4 + 3] * invn[q * 4 + 3];
    }
    wacc = wave_reduce_sum(wacc);
    __syncthreads();
    if (lane == 0) red[wv] = wacc;
    __syncthreads();
    if (tid == 0) {
        const float inv_na = ina[row];
        perstep[row] = cmaxAll * inv_na;
        wout[row] = (red[0] + red[1] + red[2] + red[3]) * inv_na;
    }
}

// ---------------- finalize scalars -----------------------------------------
__global__ __launch_bounds__(1024)
void finalize_kernel(const float* __restrict__ perstep, const float* __restrict__ w,
                     const unsigned* __restrict__ negmax_u,
                     const float* __restrict__ ina, float* __restrict__ out,
                     int N, size_t NM) {
    float s_a = 0.0f, s_w = 0.0f, s_n = 0.0f, mn = 3.4e38f;
    for (int i = threadIdx.x; i < N; i += 1024) {
        const float p = perstep[i];
        s_a += p;
        s_w += w[i];
        s_n += dec_f(negmax_u[i]) * ina[i];
        mn = fminf(mn, p);
    }
    s_a = wave_reduce_sum(s_a);
    s_w = wave_reduce_sum(s_w);
    s_n = wave_reduce_sum(s_n);
    mn  = wave_reduce_min(mn);
    __shared__ float ra[16], rw[16], rn[16], rm[16];
    const int lane = threadIdx.x & 63, wv = threadIdx.x >> 6;
    if (lane == 0) { ra[wv] = s_a; rw[wv] = s_w; rn[wv] = s_n; rm[wv] = mn; }
    __syncthreads();
    if (threadIdx.x == 0) {
        float ta = 0, tw = 0, tn = 0, tm = 3.4e38f;
#pragma unroll
        for (int i = 0; i < 16; i++) {
            ta += ra[i]; tw += rw[i]; tn += rn[i]; tm = fminf(tm, rm[i]);
        }
        const float inv = 1.0f / (float)N;
        const float alignment = ta * inv;
        const float weighted  = tw * inv;
        const float neg       = tn * inv;
        const float contrast  = alignment - neg;
        const float margin    = fmaxf(contrast - 0.2f, 0.0f);
        const float overall   = 0.7f * weighted + 0.3f * contrast;
        out[0] = alignment;
        out[1] = weighted;
        float* p = out + 2 + NM;
        p[0] = contrast;
        p[1] = margin;
        p[2] = alignment;   // positive_alignment
        p[3] = neg;
        p[4 + N] = tm;      // min_step_coherence
        p[5 + N] = overall;
    }
}

// ---------------------------------------------------------------------------
extern "C" void kernel_launch(void* const* d_in, const int* in_sizes, int n_in,
                              void* d_out, int out_size, void* d_ws, size_t ws_size,
                              hipStream_t stream) {
    const float* step  = (const float*)d_in[0];
    const float* modal = (const float*)d_in[1];
    const float* negs  = (const float*)d_in[2];
    float* out = (float*)d_out;

    const int K = 1024;
    const int N = in_sizes[0] / K;   // 8192
    const int M = in_sizes[1] / K;   // 4096
    const size_t NM = (size_t)N * (size_t)M;

    float* ina        = (float*)d_ws;          // N
    float* inb        = ina + N;               // M
    float* inn        = inb + M;               // M
    unsigned* negmax  = (unsigned*)(inn + M);  // N
    float* wsum       = (float*)(negmax + N);  // N

    char* arena    = (char*)d_out + 16;
    float* attn    = out + 2;
    float* perstep = out + 2 + NM + 4;

    // 1. convert inputs to bf16 chunks + inverse norms + init atomics
    convert_norms_kernel<<<N + 2 * M, 256, 0, stream>>>(
        step, modal, negs, arena, ina, inb, inn, negmax, N, M);

    // 2. fused GEMM: modal half stores G bf16, negatives half atomic rowmax
    dim3 grid((2 * M) / 128, N / 128);
    gemm_fused_kernel<<<grid, 256, 0, stream>>>(arena, N, M, inn, negmax);

    // 3. softmax + exact fp32 fix-up, writes fp32 attention + per-row outs
    softmax_fix_kernel<<<N, 256, 0, stream>>>(arena, step, modal, ina, inb,
                                              perstep, wsum, attn);

    // 4. scalars
    finalize_kernel<<<1, 1024, 0, stream>>>(perstep, wsum, negmax, ina, out, N, NM);
}

// Round 5
// 418.227 us; speedup vs baseline: 4.1177x; 1.0244x over previous
//
#include <hip/hip_runtime.h>
#include <cmath>

// ---------------------------------------------------------------------------
// Round 5: + supertile block swizzle in the fused GEMM (16 bm x 8 bn
// supertiles) so co-resident blocks share A/B panels in per-XCD L2 —
// round 4's FETCH_SIZE=298MB (vs 32MB of inputs) showed L2 thrash was
// feeding the per-iteration vmcnt drain with HBM/L3-latency misses.
// Convert kernel: one row per wave, no barriers (grid /4).
// Arena (inside attention output region): slot r (16 KB) =
//   [ G-bf16 row r : 8 KB | input bf16 chunks 4r..4r+3 : 8 KB ]
// chunk order: 0..N-1 step, N..N+M-1 modal, N+M..N+2M-1 negs.
// ---------------------------------------------------------------------------

#define WAVE 64

typedef __bf16 bf16x8_t __attribute__((ext_vector_type(8)));
typedef __bf16 bf16x4_t __attribute__((ext_vector_type(4)));
typedef float f32x4_t __attribute__((ext_vector_type(4)));

__device__ __forceinline__ float wave_reduce_sum(float v) {
#pragma unroll
    for (int o = 32; o > 0; o >>= 1) v += __shfl_down(v, o, WAVE);
    return v;
}
__device__ __forceinline__ float wave_reduce_max(float v) {
#pragma unroll
    for (int o = 32; o > 0; o >>= 1) v = fmaxf(v, __shfl_down(v, o, WAVE));
    return v;
}
__device__ __forceinline__ float wave_reduce_min(float v) {
#pragma unroll
    for (int o = 32; o > 0; o >>= 1) v = fminf(v, __shfl_down(v, o, WAVE));
    return v;
}

// monotone float <-> uint map for atomicMax on floats of any sign
__device__ __forceinline__ unsigned enc_f(float f) {
    unsigned u = __float_as_uint(f);
    return (u & 0x80000000u) ? ~u : (u | 0x80000000u);
}
__device__ __forceinline__ float dec_f(unsigned e) {
    unsigned u = (e & 0x80000000u) ? (e & 0x7fffffffu) : ~e;
    return __uint_as_float(u);
}

// ---------------- convert fp32 -> bf16 chunks + inverse norms --------------
// one row per WAVE (4 rows/block), no block barriers.
__global__ __launch_bounds__(256)
void convert_norms_kernel(const float* __restrict__ step,
                          const float* __restrict__ modal,
                          const float* __restrict__ negs,
                          char* __restrict__ arena,
                          float* __restrict__ ina, float* __restrict__ inb,
                          float* __restrict__ inn,
                          unsigned* __restrict__ negmax_u, int N, int M) {
    const int tid = threadIdx.x, lane = tid & 63, wv = tid >> 6;
    const int b = blockIdx.x * 4 + wv;
    const float* src;
    if (b < N)          src = step  + (size_t)b * 1024;
    else if (b < N + M) src = modal + (size_t)(b - N) * 1024;
    else                src = negs  + (size_t)(b - N - M) * 1024;

    char* cb = arena + (((size_t)(b >> 2)) << 14) + ((size_t)(b & 3) << 11) + 8192;
    float s = 0.0f;
#pragma unroll
    for (int q = 0; q < 4; q++) {
        const int idx = lane + q * 64;          // float4 index within row
        const float4 v = ((const float4*)src)[idx];
        bf16x4_t o;
        o[0] = (__bf16)v.x; o[1] = (__bf16)v.y;
        o[2] = (__bf16)v.z; o[3] = (__bf16)v.w;
        *(bf16x4_t*)(cb + (size_t)idx * 8) = o;
        s += v.x * v.x + v.y * v.y + v.z * v.z + v.w * v.w;
    }
    s = wave_reduce_sum(s);
    if (lane == 0) {
        const float inv = 1.0f / fmaxf(sqrtf(s), 1e-8f);
        if (b < N)          { ina[b] = inv; negmax_u[b] = 0u; }
        else if (b < N + M) inb[b - N] = inv;
        else                inn[b - N - M] = inv;
    }
}

// ---------------- fused bf16 MFMA GEMM over arena chunks -------------------
// 1-D grid of 4096 blocks; supertile swizzle 16(bm) x 8(bn), x-major within,
// so the ~1000 co-resident blocks share panels in per-XCD L2.
// bn < M -> modal (store G bf16); else negatives (atomic rowmax, no store).
#define GLD16(g, l)                                                        \
    __builtin_amdgcn_global_load_lds(                                     \
        (const __attribute__((address_space(1))) void*)(g),               \
        (__attribute__((address_space(3))) void*)(l), 16, 0, 0)

__global__ __launch_bounds__(256, 4)
void gemm_fused_kernel(char* __restrict__ arena, int N, int M,
                       const float* __restrict__ inv_nn,
                       unsigned* __restrict__ negmax_u) {
    __shared__ __bf16 As[128 * 64];   // 16 KB, row-major, 64 bf16 per row
    __shared__ __bf16 Bs[128 * 64];   // 16 KB

    // supertile swizzle: 16 bm-blocks x 8 bn-blocks per supertile
    const int lin = blockIdx.x;            // 0..4095
    const int st  = lin >> 7;              // 0..31
    const int r128 = lin & 127;
    const int bxi = (st & 7) * 8 + (r128 & 7);     // 0..63
    const int byi = (st >> 3) * 16 + (r128 >> 3);  // 0..63
    const int bm = byi * 128, bn = bxi * 128;

    const int t = threadIdx.x, w = t >> 6, lane = t & 63;
    const int lane16 = lane & 15, lq = lane >> 4;
    const int wm = (w & 1) * 64, wn = (w >> 1) * 64;

    // ---- staging assignment: waves 0-1 -> As halves, waves 2-3 -> Bs ----
    // lds row = rowbase + r*8 + (lane>>3); lds octet = lane&7;
    // global octet = (lane&7) ^ (row&7) = (lane&7) ^ (lane>>3)   [swizzle]
    const int s_is_b  = w >> 1;
    const int rowbase = (w & 1) * 64;
    const int ln3 = lane >> 3;
    const int q_g = (lane & 7) ^ ln3;
    const int cbase = (s_is_b ? (N + bn) : bm) + rowbase;
    const int cc = cbase + ln3;      // chunk index for r=0
    const size_t off0 = (((size_t)(cc >> 2)) << 14) +
                        ((size_t)(cc & 3) << 11) + 8192 + (size_t)q_g * 16;
    const char* gbase = arena + off0;
    __bf16* ldsw = (s_is_b ? Bs : As) + rowbase * 64;

    f32x4_t acc[4][4];
#pragma unroll
    for (int i = 0; i < 4; i++)
#pragma unroll
        for (int j = 0; j < 4; j++) acc[i][j] = (f32x4_t){0.f, 0.f, 0.f, 0.f};

    const int sxr = lane16 & 7;      // row&7 for all fragment rows

    for (int k0b = 0; k0b < 2048; k0b += 128) {   // byte offset along K
        __syncthreads();   // all waves done reading LDS from prev iter
#pragma unroll
        for (int r = 0; r < 8; r++)
            GLD16(gbase + (size_t)r * 32768 + k0b, ldsw + r * 512);
        __syncthreads();   // vmcnt drained before barrier (compiler-enforced)

#pragma unroll
        for (int kk = 0; kk < 2; kk++) {
            const int qo = ((lq + kk * 4) ^ sxr) * 8;   // swizzled octet
            bf16x8_t af[4], bf[4];
#pragma unroll
            for (int i = 0; i < 4; i++)
                af[i] = *(const bf16x8_t*)&As[(wm + i * 16 + lane16) * 64 + qo];
#pragma unroll
            for (int j = 0; j < 4; j++)
                bf[j] = *(const bf16x8_t*)&Bs[(wn + j * 16 + lane16) * 64 + qo];
#pragma unroll
            for (int i = 0; i < 4; i++)
#pragma unroll
                for (int j = 0; j < 4; j++)
                    acc[i][j] = __builtin_amdgcn_mfma_f32_16x16x32_bf16(
                        af[i], bf[j], acc[i][j], 0, 0, 0);
        }
    }

    // C/D layout (16x16x32): col = lane16, row = lq*4 + reg
    if (bn < M) {
        // modal half: store G as bf16 into slot front halves
#pragma unroll
        for (int i = 0; i < 4; i++) {
#pragma unroll
            for (int r = 0; r < 4; r++) {
                const int grow = bm + wm + i * 16 + lq * 4 + r;
                __bf16* dst = (__bf16*)(arena + ((size_t)grow << 14)) +
                              bn + wn + lane16;
#pragma unroll
                for (int j = 0; j < 4; j++)
                    dst[j * 16] = (__bf16)acc[i][j][r];
            }
        }
    } else {
        // negatives half: per-row max of dot * inv_nn[col], atomicMax per row
        float invn[4];
#pragma unroll
        for (int j = 0; j < 4; j++)
            invn[j] = inv_nn[(bn - M) + wn + j * 16 + lane16];
#pragma unroll
        for (int i = 0; i < 4; i++) {
#pragma unroll
            for (int r = 0; r < 4; r++) {
                float v = acc[i][0][r] * invn[0];
                v = fmaxf(v, acc[i][1][r] * invn[1]);
                v = fmaxf(v, acc[i][2][r] * invn[2]);
                v = fmaxf(v, acc[i][3][r] * invn[3]);
#pragma unroll
                for (int o = 8; o > 0; o >>= 1)
                    v = fmaxf(v, __shfl_xor(v, o, WAVE));
                if (lane16 == 0)
                    atomicMax(&negmax_u[bm + wm + i * 16 + lq * 4 + r], enc_f(v));
            }
        }
    }
}

// ---------------- softmax with fp32 fix-up, bf16 G -> fp32 attention -------
#define CUT 2.0f
#define MAXCAND 64

__global__ __launch_bounds__(256)
void softmax_fix_kernel(char* __restrict__ arena, const float* __restrict__ step,
                        const float* __restrict__ modal,
                        const float* __restrict__ ina, const float* __restrict__ inb,
                        float* __restrict__ perstep, float* __restrict__ wout,
                        float* __restrict__ attn) {
    const int row = blockIdx.x, tid = threadIdx.x;
    const int lane = tid & 63, wv = tid >> 6;

    __shared__ float srow_s[1024];
    __shared__ float red[8];
    __shared__ float bcast[2];
    __shared__ int   cand[MAXCAND];
    __shared__ float exact[MAXCAND];
    __shared__ int   cnt;

    if (tid == 0) cnt = 0;
    ((float4*)srow_s)[tid] = ((const float4*)(step + (size_t)row * 1024))[tid];

    // thread tid owns cols tid*16 .. tid*16+15
    const __bf16* gb = (const __bf16*)(arena + ((size_t)row << 14)) + tid * 16;
    float vals[16];
    {
        bf16x8_t v0 = *(const bf16x8_t*)gb;
        bf16x8_t v1 = *(const bf16x8_t*)(gb + 8);
#pragma unroll
        for (int j = 0; j < 8; j++) { vals[j] = (float)v0[j]; vals[8 + j] = (float)v1[j]; }
    }
    float invn[16];
    {
        const float4* p = (const float4*)(inb + tid * 16);
#pragma unroll
        for (int q = 0; q < 4; q++) {
            const float4 x = p[q];
            invn[q * 4 + 0] = x.x; invn[q * 4 + 1] = x.y;
            invn[q * 4 + 2] = x.z; invn[q * 4 + 3] = x.w;
        }
    }

    float dmax = -3.4e38f;
#pragma unroll
    for (int j = 0; j < 16; j++) dmax = fmaxf(dmax, vals[j]);
    float wm = wave_reduce_max(dmax);
    if (lane == 0) red[wv] = wm;
    __syncthreads();   // also covers cnt=0 and srow_s
    if (tid == 0) bcast[0] = fmaxf(fmaxf(red[0], red[1]), fmaxf(red[2], red[3]));
    __syncthreads();
    const float m0 = bcast[0];

    // collect candidates within CUT of the (bf16-accuracy) max
    const float thr = m0 - CUT;
#pragma unroll
    for (int j = 0; j < 16; j++) {
        if (vals[j] >= thr) {
            const int pos = atomicAdd(&cnt, 1);
            if (pos < MAXCAND) cand[pos] = tid * 16 + j;
        }
    }
    __syncthreads();
    const int nc = min(cnt, MAXCAND);

    // exact fp32 dots, one candidate per wave (no block barriers inside)
    for (int i = wv; i < nc; i += 4) {
        const float* mrow = modal + (size_t)cand[i] * 1024;
        float p = 0.0f;
#pragma unroll
        for (int q = 0; q < 16; q++) {
            const int idx = lane + q * 64;
            p = fmaf(srow_s[idx], mrow[idx], p);
        }
        p = wave_reduce_sum(p);
        if (lane == 0) exact[i] = p;
    }
    __syncthreads();

    // substitute exact values
    for (int i = 0; i < nc; i++) {
        const int c = cand[i];
        if ((c >> 4) == tid) vals[c & 15] = exact[i];
    }

    // corrected dot max + cosine max
    float dmax2 = -3.4e38f, cmax = -3.4e38f;
#pragma unroll
    for (int j = 0; j < 16; j++) {
        dmax2 = fmaxf(dmax2, vals[j]);
        cmax = fmaxf(cmax, vals[j] * invn[j]);
    }
    float wg = wave_reduce_max(dmax2);
    float wc = wave_reduce_max(cmax);
    if (lane == 0) { red[wv] = wg; red[4 + wv] = wc; }
    __syncthreads();
    if (tid == 0) {
        bcast[0] = fmaxf(fmaxf(red[0], red[1]), fmaxf(red[2], red[3]));
        bcast[1] = fmaxf(fmaxf(red[4], red[5]), fmaxf(red[6], red[7]));
    }
    __syncthreads();
    const float invT = 1.0f / 0.07f;
    const float mlog = bcast[0] * invT;
    const float cmaxAll = bcast[1];

    float evals[16];
    float lsum = 0.0f;
#pragma unroll
    for (int j = 0; j < 16; j++) {
        const float e = __expf(vals[j] * invT - mlog);
        evals[j] = e;
        lsum += e;
    }
    lsum = wave_reduce_sum(lsum);
    __syncthreads();
    if (lane == 0) red[wv] = lsum;
    __syncthreads();
    if (tid == 0) bcast[0] = red[0] + red[1] + red[2] + red[3];
    __syncthreads();
    const float invZ = 1.0f / bcast[0];

    float* g32 = attn + (size_t)row * 4096 + tid * 16;
    float wacc = 0.0f;
#pragma unroll
    for (int q = 0; q < 4; q++) {
        float4 o;
        float a0 = evals[q * 4 + 0] * invZ, a1 = evals[q * 4 + 1] * invZ;
        float a2 = evals[q * 4 + 2] * invZ, a3 = evals[q * 4 + 3] * invZ;
        o.x = a0; o.y = a1; o.z = a2; o.w = a3;
        ((float4*)g32)[q] = o;
        wacc += a0 * vals[q * 4 + 0] * invn[q * 4 + 0];
        wacc += a1 * vals[q * 4 + 1] * invn[q * 4 + 1];
        wacc += a2 * vals[q * 4 + 2] * invn[q * 4 + 2];
        wacc += a3 * vals[q * 4 + 3] * invn[q * 4 + 3];
    }
    wacc = wave_reduce_sum(wacc);
    __syncthreads();
    if (lane == 0) red[wv] = wacc;
    __syncthreads();
    if (tid == 0) {
        const float inv_na = ina[row];
        perstep[row] = cmaxAll * inv_na;
        wout[row] = (red[0] + red[1] + red[2] + red[3]) * inv_na;
    }
}

// ---------------- finalize scalars -----------------------------------------
__global__ __launch_bounds__(1024)
void finalize_kernel(const float* __restrict__ perstep, const float* __restrict__ w,
                     const unsigned* __restrict__ negmax_u,
                     const float* __restrict__ ina, float* __restrict__ out,
                     int N, size_t NM) {
    float s_a = 0.0f, s_w = 0.0f, s_n = 0.0f, mn = 3.4e38f;
    for (int i = threadIdx.x; i < N; i += 1024) {
        const float p = perstep[i];
        s_a += p;
        s_w += w[i];
        s_n += dec_f(negmax_u[i]) * ina[i];
        mn = fminf(mn, p);
    }
    s_a = wave_reduce_sum(s_a);
    s_w = wave_reduce_sum(s_w);
    s_n = wave_reduce_sum(s_n);
    mn  = wave_reduce_min(mn);
    __shared__ float ra[16], rw[16], rn[16], rm[16];
    const int lane = threadIdx.x & 63, wv = threadIdx.x >> 6;
    if (lane == 0) { ra[wv] = s_a; rw[wv] = s_w; rn[wv] = s_n; rm[wv] = mn; }
    __syncthreads();
    if (threadIdx.x == 0) {
        float ta = 0, tw = 0, tn = 0, tm = 3.4e38f;
#pragma unroll
        for (int i = 0; i < 16; i++) {
            ta += ra[i]; tw += rw[i]; tn += rn[i]; tm = fminf(tm, rm[i]);
        }
        const float inv = 1.0f / (float)N;
        const float alignment = ta * inv;
        const float weighted  = tw * inv;
        const float neg       = tn * inv;
        const float contrast  = alignment - neg;
        const float margin    = fmaxf(contrast - 0.2f, 0.0f);
        const float overall   = 0.7f * weighted + 0.3f * contrast;
        out[0] = alignment;
        out[1] = weighted;
        float* p = out + 2 + NM;
        p[0] = contrast;
        p[1] = margin;
        p[2] = alignment;   // positive_alignment
        p[3] = neg;
        p[4 + N] = tm;      // min_step_coherence
        p[5 + N] = overall;
    }
}

// ---------------------------------------------------------------------------
extern "C" void kernel_launch(void* const* d_in, const int* in_sizes, int n_in,
                              void* d_out, int out_size, void* d_ws, size_t ws_size,
                              hipStream_t stream) {
    const float* step  = (const float*)d_in[0];
    const float* modal = (const float*)d_in[1];
    const float* negs  = (const float*)d_in[2];
    float* out = (float*)d_out;

    const int K = 1024;
    const int N = in_sizes[0] / K;   // 8192
    const int M = in_sizes[1] / K;   // 4096
    const size_t NM = (size_t)N * (size_t)M;

    float* ina        = (float*)d_ws;          // N
    float* inb        = ina + N;               // M
    float* inn        = inb + M;               // M
    unsigned* negmax  = (unsigned*)(inn + M);  // N
    float* wsum       = (float*)(negmax + N);  // N

    char* arena    = (char*)d_out + 16;
    float* attn    = out + 2;
    float* perstep = out + 2 + NM + 4;

    // 1. convert inputs to bf16 chunks + inverse norms + init atomics
    convert_norms_kernel<<<(N + 2 * M) / 4, 256, 0, stream>>>(
        step, modal, negs, arena, ina, inb, inn, negmax, N, M);

    // 2. fused GEMM (supertile-swizzled 1-D grid)
    const int nblocks = (N / 128) * ((2 * M) / 128);
    gemm_fused_kernel<<<nblocks, 256, 0, stream>>>(arena, N, M, inn, negmax);

    // 3. softmax + exact fp32 fix-up, writes fp32 attention + per-row outs
    softmax_fix_kernel<<<N, 256, 0, stream>>>(arena, step, modal, ina, inb,
                                              perstep, wsum, attn);

    // 4. scalars
    finalize_kernel<<<1, 1024, 0, stream>>>(perstep, wsum, negmax, ina, out, N, NM);
}

// Round 6
// 398.906 us; speedup vs baseline: 4.3171x; 1.0484x over previous
//
#include <hip/hip_runtime.h>
#include <cmath>

// ---------------------------------------------------------------------------
// Round 6:
// (a) GEMM: double-buffered LDS (2x32KB, 2 blocks/CU) with ONE raw barrier
//     per K-iter (asm s_waitcnt vmcnt(0) lgkmcnt(0); s_barrier) and next-tile
//     global_load_lds issued after the barrier so the loads stay in flight
//     across the whole ds_read+MFMA phase (AITER-style pipeline).
// (b) softmax: coalesced column grouping (col = g*1024 + tid*4 + u) so attn
//     float4 stores / G reads are lane-dense (round-5 layout had 64B-stride
//     lanes -> 4x RMW write amplification on 134 MB).
// Arena (inside attention output region): slot r (16 KB) =
//   [ G-bf16 row r : 8 KB | input bf16 chunks 4r..4r+3 : 8 KB ]
// chunk order: 0..N-1 step, N..N+M-1 modal, N+M..N+2M-1 negs.
// ---------------------------------------------------------------------------

#define WAVE 64

typedef __bf16 bf16x8_t __attribute__((ext_vector_type(8)));
typedef __bf16 bf16x4_t __attribute__((ext_vector_type(4)));
typedef float f32x4_t __attribute__((ext_vector_type(4)));

__device__ __forceinline__ float wave_reduce_sum(float v) {
#pragma unroll
    for (int o = 32; o > 0; o >>= 1) v += __shfl_down(v, o, WAVE);
    return v;
}
__device__ __forceinline__ float wave_reduce_max(float v) {
#pragma unroll
    for (int o = 32; o > 0; o >>= 1) v = fmaxf(v, __shfl_down(v, o, WAVE));
    return v;
}
__device__ __forceinline__ float wave_reduce_min(float v) {
#pragma unroll
    for (int o = 32; o > 0; o >>= 1) v = fminf(v, __shfl_down(v, o, WAVE));
    return v;
}

// monotone float <-> uint map for atomicMax on floats of any sign
__device__ __forceinline__ unsigned enc_f(float f) {
    unsigned u = __float_as_uint(f);
    return (u & 0x80000000u) ? ~u : (u | 0x80000000u);
}
__device__ __forceinline__ float dec_f(unsigned e) {
    unsigned u = (e & 0x80000000u) ? (e & 0x7fffffffu) : ~e;
    return __uint_as_float(u);
}

// ---------------- convert fp32 -> bf16 chunks + inverse norms --------------
__global__ __launch_bounds__(256)
void convert_norms_kernel(const float* __restrict__ step,
                          const float* __restrict__ modal,
                          const float* __restrict__ negs,
                          char* __restrict__ arena,
                          float* __restrict__ ina, float* __restrict__ inb,
                          float* __restrict__ inn,
                          unsigned* __restrict__ negmax_u, int N, int M) {
    const int tid = threadIdx.x, lane = tid & 63, wv = tid >> 6;
    const int b = blockIdx.x * 4 + wv;
    const float* src;
    if (b < N)          src = step  + (size_t)b * 1024;
    else if (b < N + M) src = modal + (size_t)(b - N) * 1024;
    else                src = negs  + (size_t)(b - N - M) * 1024;

    char* cb = arena + (((size_t)(b >> 2)) << 14) + ((size_t)(b & 3) << 11) + 8192;
    float s = 0.0f;
#pragma unroll
    for (int q = 0; q < 4; q++) {
        const int idx = lane + q * 64;
        const float4 v = ((const float4*)src)[idx];
        bf16x4_t o;
        o[0] = (__bf16)v.x; o[1] = (__bf16)v.y;
        o[2] = (__bf16)v.z; o[3] = (__bf16)v.w;
        *(bf16x4_t*)(cb + (size_t)idx * 8) = o;
        s += v.x * v.x + v.y * v.y + v.z * v.z + v.w * v.w;
    }
    s = wave_reduce_sum(s);
    if (lane == 0) {
        const float inv = 1.0f / fmaxf(sqrtf(s), 1e-8f);
        if (b < N)          { ina[b] = inv; negmax_u[b] = 0u; }
        else if (b < N + M) inb[b - N] = inv;
        else                inn[b - N - M] = inv;
    }
}

// ---------------- pipelined fused bf16 MFMA GEMM ---------------------------
#define GLD16(g, l)                                                        \
    __builtin_amdgcn_global_load_lds(                                     \
        (const __attribute__((address_space(1))) void*)(g),               \
        (__attribute__((address_space(3))) void*)(l), 16, 0, 0)

// wait my outstanding loads + ds ops, then block barrier (no extra drain)
#define PIPE_BARRIER() asm volatile(                                       \
    "s_waitcnt vmcnt(0) lgkmcnt(0)\n\ts_barrier" ::: "memory")

__global__ __launch_bounds__(256, 2)
void gemm_fused_kernel(char* __restrict__ arena, int N, int M,
                       const float* __restrict__ inv_nn,
                       unsigned* __restrict__ negmax_u) {
    __shared__ __bf16 As[2][128 * 64];   // 2 x 16 KB
    __shared__ __bf16 Bs[2][128 * 64];   // 2 x 16 KB

    // supertile swizzle: 16 bm-blocks x 8 bn-blocks per supertile
    const int lin = blockIdx.x;            // 0..4095
    const int st  = lin >> 7;
    const int r128 = lin & 127;
    const int bxi = (st & 7) * 8 + (r128 & 7);
    const int byi = (st >> 3) * 16 + (r128 >> 3);
    const int bm = byi * 128, bn = bxi * 128;

    const int t = threadIdx.x, w = t >> 6, lane = t & 63;
    const int lane16 = lane & 15, lq = lane >> 4;
    const int wm = (w & 1) * 64, wn = (w >> 1) * 64;

    // staging: waves 0-1 -> As halves, waves 2-3 -> Bs halves
    // lds row = rowbase + r*8 + (lane>>3); lds octet = lane&7
    // global octet = (lane&7) ^ (lane>>3)   [xor swizzle]
    const int s_is_b  = w >> 1;
    const int rowbase = (w & 1) * 64;
    const int ln3 = lane >> 3;
    const int q_g = (lane & 7) ^ ln3;
    const int cbase = (s_is_b ? (N + bn) : bm) + rowbase;
    const int cc = cbase + ln3;
    const size_t off0 = (((size_t)(cc >> 2)) << 14) +
                        ((size_t)(cc & 3) << 11) + 8192 + (size_t)q_g * 16;
    const char* gbase = arena + off0;
    const int ldsoff = rowbase * 64;
    __bf16* ldsw0 = (s_is_b ? Bs[0] : As[0]) + ldsoff;
    __bf16* ldsw1 = (s_is_b ? Bs[1] : As[1]) + ldsoff;

    f32x4_t acc[4][4];
#pragma unroll
    for (int i = 0; i < 4; i++)
#pragma unroll
        for (int j = 0; j < 4; j++) acc[i][j] = (f32x4_t){0.f, 0.f, 0.f, 0.f};

    const int sxr = lane16 & 7;

    // prologue: tile 0 -> buffer 0
#pragma unroll
    for (int r = 0; r < 8; r++)
        GLD16(gbase + (size_t)r * 32768, ldsw0 + r * 512);

    for (int it = 0; it < 16; ++it) {
        PIPE_BARRIER();          // my prev loads landed + everyone's too
        const int cur = it & 1;

        // pull all fragments for this tile into registers (both kk phases)
        bf16x8_t af[2][4], bf[2][4];
#pragma unroll
        for (int kk = 0; kk < 2; kk++) {
            const int qo = ((lq + kk * 4) ^ sxr) * 8;
#pragma unroll
            for (int i = 0; i < 4; i++)
                af[kk][i] = *(const bf16x8_t*)&As[cur][(wm + i * 16 + lane16) * 64 + qo];
#pragma unroll
            for (int j = 0; j < 4; j++)
                bf[kk][j] = *(const bf16x8_t*)&Bs[cur][(wn + j * 16 + lane16) * 64 + qo];
        }

        // issue next tile's loads into the other buffer; they stay in
        // flight across the MFMA phase (waited at next PIPE_BARRIER)
        if (it + 1 < 16) {
            const size_t k0b = (size_t)(it + 1) * 128;
            __bf16* ldsw = cur ? ldsw0 : ldsw1;
#pragma unroll
            for (int r = 0; r < 8; r++)
                GLD16(gbase + (size_t)r * 32768 + k0b, ldsw + r * 512);
        }

#pragma unroll
        for (int kk = 0; kk < 2; kk++)
#pragma unroll
            for (int i = 0; i < 4; i++)
#pragma unroll
                for (int j = 0; j < 4; j++)
                    acc[i][j] = __builtin_amdgcn_mfma_f32_16x16x32_bf16(
                        af[kk][i], bf[kk][j], acc[i][j], 0, 0, 0);
    }

    // C/D layout (16x16x32): col = lane16, row = lq*4 + reg
    if (bn < M) {
#pragma unroll
        for (int i = 0; i < 4; i++) {
#pragma unroll
            for (int r = 0; r < 4; r++) {
                const int grow = bm + wm + i * 16 + lq * 4 + r;
                __bf16* dst = (__bf16*)(arena + ((size_t)grow << 14)) +
                              bn + wn + lane16;
#pragma unroll
                for (int j = 0; j < 4; j++)
                    dst[j * 16] = (__bf16)acc[i][j][r];
            }
        }
    } else {
        float invn[4];
#pragma unroll
        for (int j = 0; j < 4; j++)
            invn[j] = inv_nn[(bn - M) + wn + j * 16 + lane16];
#pragma unroll
        for (int i = 0; i < 4; i++) {
#pragma unroll
            for (int r = 0; r < 4; r++) {
                float v = acc[i][0][r] * invn[0];
                v = fmaxf(v, acc[i][1][r] * invn[1]);
                v = fmaxf(v, acc[i][2][r] * invn[2]);
                v = fmaxf(v, acc[i][3][r] * invn[3]);
#pragma unroll
                for (int o = 8; o > 0; o >>= 1)
                    v = fmaxf(v, __shfl_xor(v, o, WAVE));
                if (lane16 == 0)
                    atomicMax(&negmax_u[bm + wm + i * 16 + lq * 4 + r], enc_f(v));
            }
        }
    }
}

// ---------------- softmax with fp32 fix-up, coalesced layout ---------------
// thread tid owns cols { g*1024 + tid*4 + u : g in 0..3, u in 0..3 } so all
// global accesses are lane-dense.
#define CUT 2.0f
#define MAXCAND 64

__global__ __launch_bounds__(256)
void softmax_fix_kernel(char* __restrict__ arena, const float* __restrict__ step,
                        const float* __restrict__ modal,
                        const float* __restrict__ ina, const float* __restrict__ inb,
                        float* __restrict__ perstep, float* __restrict__ wout,
                        float* __restrict__ attn) {
    const int row = blockIdx.x, tid = threadIdx.x;
    const int lane = tid & 63, wv = tid >> 6;

    __shared__ float srow_s[1024];
    __shared__ float red[8];
    __shared__ float bcast[2];
    __shared__ int   cand[MAXCAND];
    __shared__ float exact[MAXCAND];
    __shared__ int   cnt;

    if (tid == 0) cnt = 0;
    ((float4*)srow_s)[tid] = ((const float4*)(step + (size_t)row * 1024))[tid];

    const __bf16* gb = (const __bf16*)(arena + ((size_t)row << 14));
    float vals[16];
    float invn[16];
#pragma unroll
    for (int g = 0; g < 4; g++) {
        const bf16x4_t v = *(const bf16x4_t*)(gb + g * 1024 + tid * 4);
        const float4 x = *(const float4*)(inb + g * 1024 + tid * 4);
        vals[g * 4 + 0] = (float)v[0]; vals[g * 4 + 1] = (float)v[1];
        vals[g * 4 + 2] = (float)v[2]; vals[g * 4 + 3] = (float)v[3];
        invn[g * 4 + 0] = x.x; invn[g * 4 + 1] = x.y;
        invn[g * 4 + 2] = x.z; invn[g * 4 + 3] = x.w;
    }

    float dmax = -3.4e38f;
#pragma unroll
    for (int j = 0; j < 16; j++) dmax = fmaxf(dmax, vals[j]);
    float wm = wave_reduce_max(dmax);
    if (lane == 0) red[wv] = wm;
    __syncthreads();   // also covers cnt=0 and srow_s
    if (tid == 0) bcast[0] = fmaxf(fmaxf(red[0], red[1]), fmaxf(red[2], red[3]));
    __syncthreads();
    const float m0 = bcast[0];

    // collect candidates within CUT of the (bf16-accuracy) max
    const float thr = m0 - CUT;
#pragma unroll
    for (int g = 0; g < 4; g++)
#pragma unroll
        for (int u = 0; u < 4; u++) {
            if (vals[g * 4 + u] >= thr) {
                const int pos = atomicAdd(&cnt, 1);
                if (pos < MAXCAND) cand[pos] = g * 1024 + tid * 4 + u;
            }
        }
    __syncthreads();
    const int nc = min(cnt, MAXCAND);

    // exact fp32 dots, one candidate per wave
    for (int i = wv; i < nc; i += 4) {
        const float* mrow = modal + (size_t)cand[i] * 1024;
        float p = 0.0f;
#pragma unroll
        for (int q = 0; q < 16; q++) {
            const int idx = lane + q * 64;
            p = fmaf(srow_s[idx], mrow[idx], p);
        }
        p = wave_reduce_sum(p);
        if (lane == 0) exact[i] = p;
    }
    __syncthreads();

    // substitute exact values
    for (int i = 0; i < nc; i++) {
        const int c = cand[i];
        if (((c & 1023) >> 2) == tid) vals[(c >> 10) * 4 + (c & 3)] = exact[i];
    }

    // corrected dot max + cosine max
    float dmax2 = -3.4e38f, cmax = -3.4e38f;
#pragma unroll
    for (int j = 0; j < 16; j++) {
        dmax2 = fmaxf(dmax2, vals[j]);
        cmax = fmaxf(cmax, vals[j] * invn[j]);
    }
    float wg = wave_reduce_max(dmax2);
    float wc = wave_reduce_max(cmax);
    if (lane == 0) { red[wv] = wg; red[4 + wv] = wc; }
    __syncthreads();
    if (tid == 0) {
        bcast[0] = fmaxf(fmaxf(red[0], red[1]), fmaxf(red[2], red[3]));
        bcast[1] = fmaxf(fmaxf(red[4], red[5]), fmaxf(red[6], red[7]));
    }
    __syncthreads();
    const float invT = 1.0f / 0.07f;
    const float mlog = bcast[0] * invT;
    const float cmaxAll = bcast[1];

    float evals[16];
    float lsum = 0.0f;
#pragma unroll
    for (int j = 0; j < 16; j++) {
        const float e = __expf(vals[j] * invT - mlog);
        evals[j] = e;
        lsum += e;
    }
    lsum = wave_reduce_sum(lsum);
    __syncthreads();
    if (lane == 0) red[wv] = lsum;
    __syncthreads();
    if (tid == 0) bcast[0] = red[0] + red[1] + red[2] + red[3];
    __syncthreads();
    const float invZ = 1.0f / bcast[0];

    float* arow = attn + (size_t)row * 4096;
    float wacc = 0.0f;
#pragma unroll
    for (int g = 0; g < 4; g++) {
        float4 o;
        const float a0 = evals[g * 4 + 0] * invZ, a1 = evals[g * 4 + 1] * invZ;
        const float a2 = evals[g * 4 + 2] * invZ, a3 = evals[g * 4 + 3] * invZ;
        o.x = a0; o.y = a1; o.z = a2; o.w = a3;
        *(float4*)(arow + g * 1024 + tid * 4) = o;
        wacc += a0 * vals[g * 4 + 0] * invn[g * 4 + 0];
        wacc += a1 * vals[g * 4 + 1] * invn[g * 4 + 1];
        wacc += a2 * vals[g * 4 + 2] * invn[g * 4 + 2];
        wacc += a3 * vals[g * 4 + 3] * invn[g * 4 + 3];
    }
    wacc = wave_reduce_sum(wacc);
    __syncthreads();
    if (lane == 0) red[wv] = wacc;
    __syncthreads();
    if (tid == 0) {
        const float inv_na = ina[row];
        perstep[row] = cmaxAll * inv_na;
        wout[row] = (red[0] + red[1] + red[2] + red[3]) * inv_na;
    }
}

// ---------------- finalize scalars -----------------------------------------
__global__ __launch_bounds__(1024)
void finalize_kernel(const float* __restrict__ perstep, const float* __restrict__ w,
                     const unsigned* __restrict__ negmax_u,
                     const float* __restrict__ ina, float* __restrict__ out,
                     int N, size_t NM) {
    float s_a = 0.0f, s_w = 0.0f, s_n = 0.0f, mn = 3.4e38f;
    for (int i = threadIdx.x; i < N; i += 1024) {
        const float p = perstep[i];
        s_a += p;
        s_w += w[i];
        s_n += dec_f(negmax_u[i]) * ina[i];
        mn = fminf(mn, p);
    }
    s_a = wave_reduce_sum(s_a);
    s_w = wave_reduce_sum(s_w);
    s_n = wave_reduce_sum(s_n);
    mn  = wave_reduce_min(mn);
    __shared__ float ra[16], rw[16], rn[16], rm[16];
    const int lane = threadIdx.x & 63, wv = threadIdx.x >> 6;
    if (lane == 0) { ra[wv] = s_a; rw[wv] = s_w; rn[wv] = s_n; rm[wv] = mn; }
    __syncthreads();
    if (threadIdx.x == 0) {
        float ta = 0, tw = 0, tn = 0, tm = 3.4e38f;
#pragma unroll
        for (int i = 0; i < 16; i++) {
            ta += ra[i]; tw += rw[i]; tn += rn[i]; tm = fminf(tm, rm[i]);
        }
        const float inv = 1.0f / (float)N;
        const float alignment = ta * inv;
        const float weighted  = tw * inv;
        const float neg       = tn * inv;
        const float contrast  = alignment - neg;
        const float margin    = fmaxf(contrast - 0.2f, 0.0f);
        const float overall   = 0.7f * weighted + 0.3f * contrast;
        out[0] = alignment;
        out[1] = weighted;
        float* p = out + 2 + NM;
        p[0] = contrast;
        p[1] = margin;
        p[2] = alignment;   // positive_alignment
        p[3] = neg;
        p[4 + N] = tm;      // min_step_coherence
        p[5 + N] = overall;
    }
}

// ---------------------------------------------------------------------------
extern "C" void kernel_launch(void* const* d_in, const int* in_sizes, int n_in,
                              void* d_out, int out_size, void* d_ws, size_t ws_size,
                              hipStream_t stream) {
    const float* step  = (const float*)d_in[0];
    const float* modal = (const float*)d_in[1];
    const float* negs  = (const float*)d_in[2];
    float* out = (float*)d_out;

    const int K = 1024;
    const int N = in_sizes[0] / K;   // 8192
    const int M = in_sizes[1] / K;   // 4096
    const size_t NM = (size_t)N * (size_t)M;

    float* ina        = (float*)d_ws;          // N
    float* inb        = ina + N;               // M
    float* inn        = inb + M;               // M
    unsigned* negmax  = (unsigned*)(inn + M);  // N
    float* wsum       = (float*)(negmax + N);  // N

    char* arena    = (char*)d_out + 16;
    float* attn    = out + 2;
    float* perstep = out + 2 + NM + 4;

    // 1. convert inputs to bf16 chunks + inverse norms + init atomics
    convert_norms_kernel<<<(N + 2 * M) / 4, 256, 0, stream>>>(
        step, modal, negs, arena, ina, inb, inn, negmax, N, M);

    // 2. pipelined fused GEMM (supertile-swizzled 1-D grid)
    const int nblocks = (N / 128) * ((2 * M) / 128);
    gemm_fused_kernel<<<nblocks, 256, 0, stream>>>(arena, N, M, inn, negmax);

    // 3. softmax + exact fp32 fix-up, writes fp32 attention + per-row outs
    softmax_fix_kernel<<<N, 256, 0, stream>>>(arena, step, modal, ina, inb,
                                              perstep, wsum, attn);

    // 4. scalars
    finalize_kernel<<<1, 1024, 0, stream>>>(perstep, wsum, negmax, ina, out, N, NM);
}